// Round 5
// baseline (257.683 us; speedup 1.0000x reference)
//
#include <hip/hip_runtime.h>
#include <hip/hip_bf16.h>
#include <cstdint>

#define D_MODEL 2048
#define N_BATCH 16384

typedef __attribute__((ext_vector_type(8))) __bf16 bf16x8;
typedef __attribute__((ext_vector_type(4))) float f32x4;

__device__ __forceinline__ unsigned short f2bf(float f) {
    unsigned int u = __builtin_bit_cast(unsigned int, f);
    u += 0x7fffu + ((u >> 16) & 1u);
    return (unsigned short)(u >> 16);
}

// ---------------- LayerNorm: x fp32 [B][D] -> h bf16 [B][D] ----------------
__global__ __launch_bounds__(256) void ln_kernel(
    const float* __restrict__ x, const float* __restrict__ gamma,
    const float* __restrict__ beta, unsigned short* __restrict__ h)
{
    const int row = blockIdx.x;
    const int t = threadIdx.x;
    const float4* x4 = reinterpret_cast<const float4*>(x + (long)row * D_MODEL);
    float4 a = x4[t];
    float4 b = x4[256 + t];
    float s  = a.x + a.y + a.z + a.w + b.x + b.y + b.z + b.w;
    float ss = a.x*a.x + a.y*a.y + a.z*a.z + a.w*a.w
             + b.x*b.x + b.y*b.y + b.z*b.z + b.w*b.w;
    #pragma unroll
    for (int off = 32; off; off >>= 1) {
        s  += __shfl_xor(s, off);
        ss += __shfl_xor(ss, off);
    }
    __shared__ float red[8];
    const int lane = t & 63, wid = t >> 6;
    if (lane == 0) { red[wid*2] = s; red[wid*2+1] = ss; }
    __syncthreads();
    s  = red[0] + red[2] + red[4] + red[6];
    ss = red[1] + red[3] + red[5] + red[7];
    const float mean = s * (1.0f / D_MODEL);
    const float var  = ss * (1.0f / D_MODEL) - mean * mean;
    const float inv  = rsqrtf(var + 1e-5f);

    const float4* g4  = reinterpret_cast<const float4*>(gamma);
    const float4* be4 = reinterpret_cast<const float4*>(beta);
    ushort4* h4 = reinterpret_cast<ushort4*>(h + (long)row * D_MODEL);
    {
        float4 g = g4[t], be = be4[t];
        ushort4 o;
        o.x = f2bf((a.x - mean) * inv * g.x + be.x);
        o.y = f2bf((a.y - mean) * inv * g.y + be.y);
        o.z = f2bf((a.z - mean) * inv * g.z + be.z);
        o.w = f2bf((a.w - mean) * inv * g.w + be.w);
        h4[t] = o;
    }
    {
        float4 g = g4[256 + t], be = be4[256 + t];
        ushort4 o;
        o.x = f2bf((b.x - mean) * inv * g.x + be.x);
        o.y = f2bf((b.y - mean) * inv * g.y + be.y);
        o.z = f2bf((b.z - mean) * inv * g.z + be.z);
        o.w = f2bf((b.w - mean) * inv * g.w + be.w);
        h4[256 + t] = o;
    }
}

// ------------- transpose + convert: out[k][j] = bf16(in[j][k]) -------------
__global__ __launch_bounds__(256) void transpose_f32_to_bf16(
    const float* __restrict__ in, unsigned short* __restrict__ out, int Dm)
{
    __shared__ float tile[32][33];
    const int nb = Dm >> 5;
    const int k0 = (blockIdx.x % nb) * 32;
    const int j0 = (blockIdx.x / nb) * 32;
    const int tx = threadIdx.x & 31, ty0 = threadIdx.x >> 5;
    #pragma unroll
    for (int i = 0; i < 32; i += 8) {
        int j = ty0 + i;
        tile[j][tx] = in[(long)(j0 + j) * Dm + k0 + tx];
    }
    __syncthreads();
    #pragma unroll
    for (int i = 0; i < 32; i += 8) {
        int kk = ty0 + i;
        out[(long)(k0 + kk) * Dm + j0 + tx] = f2bf(tile[tx][kk]);
    }
}

// ---------------- elementwise convert fp32 -> bf16 ----------------
__global__ __launch_bounds__(256) void convert_bf16(
    const float* __restrict__ in, unsigned short* __restrict__ out, long n)
{
    long i = ((long)blockIdx.x * 256 + threadIdx.x) * 8;
    if (i >= n) return;
    const float4* in4 = reinterpret_cast<const float4*>(in + i);
    float4 a = in4[0], b = in4[1];
    union { unsigned short u[8]; uint4 v; } o;
    o.u[0] = f2bf(a.x); o.u[1] = f2bf(a.y); o.u[2] = f2bf(a.z); o.u[3] = f2bf(a.w);
    o.u[4] = f2bf(b.x); o.u[5] = f2bf(b.y); o.u[6] = f2bf(b.z); o.u[7] = f2bf(b.w);
    *reinterpret_cast<uint4*>(out + i) = o.v;
}

// ---------------- b_c[n] = b_o[n] + sum_j w_o[n][j]*b_v[j] (fp32) ----------------
__global__ __launch_bounds__(256) void bias_combine(
    const float* __restrict__ w_o, const float* __restrict__ b_v,
    const float* __restrict__ b_o, float* __restrict__ b_c)
{
    const int n = blockIdx.x;
    const int t = threadIdx.x;
    const float4* w4 = reinterpret_cast<const float4*>(w_o + (long)n * D_MODEL);
    const float4* v4 = reinterpret_cast<const float4*>(b_v);
    float4 a = w4[t], b = w4[256 + t], va = v4[t], vb = v4[256 + t];
    float s = a.x*va.x + a.y*va.y + a.z*va.z + a.w*va.w
            + b.x*vb.x + b.y*vb.y + b.z*vb.z + b.w*vb.w;
    #pragma unroll
    for (int off = 32; off; off >>= 1) s += __shfl_xor(s, off);
    __shared__ float red[4];
    const int lane = t & 63, wid = t >> 6;
    if (lane == 0) red[wid] = s;
    __syncthreads();
    if (t == 0) b_c[n] = red[0] + red[1] + red[2] + red[3] + b_o[n];
}

// ---------------- small BT-GEMM (128x128 tile, m97 structure), bf16 out ----------------
__global__ __launch_bounds__(256, 2) void gemm_bt_128(
    const unsigned short* __restrict__ A, const unsigned short* __restrict__ B,
    unsigned short* __restrict__ C, int M, int N, int K)
{
    const int nBN = N >> 7;
    int wg = blockIdx.x;
    const int nwg = gridDim.x;
    const int cpx = nwg >> 3;
    wg = (wg & 7) * cpx + (wg >> 3);
    const int bm = wg / nBN, bn = wg % nBN;

    const int t = threadIdx.x;
    const int lane = t & 63, wid = t >> 6;
    const int wr = wid >> 1, wc = wid & 1;

    __shared__ __align__(16) unsigned short Alds[128 * 32];
    __shared__ __align__(16) unsigned short Blds[128 * 32];

    f32x4 acc[4][4];
    #pragma unroll
    for (int i = 0; i < 4; i++)
        #pragma unroll
        for (int j = 0; j < 4; j++) acc[i][j] = (f32x4){0.f, 0.f, 0.f, 0.f};

    const long Abase = (long)bm * 128 * K;
    const long Bbase = (long)bn * 128 * K;
    const int ci0 = wid * 64 + lane;
    const int ci1 = 256 + ci0;
    const int r0 = ci0 >> 2, c0 = (ci0 & 3) * 8;
    const int r1 = ci1 >> 2, c1 = (ci1 & 3) * 8;

    const int arow = wr * 64 + (lane & 15);
    const int brow = wc * 64 + (lane & 15);
    const int koff = (lane >> 4) * 8;

    for (int k0 = 0; k0 < K; k0 += 32) {
        __builtin_amdgcn_global_load_lds(
            (const __attribute__((address_space(1))) void*)(A + Abase + (long)r0 * K + k0 + c0),
            (__attribute__((address_space(3))) void*)(Alds + wid * 512), 16, 0, 0);
        __builtin_amdgcn_global_load_lds(
            (const __attribute__((address_space(1))) void*)(A + Abase + (long)r1 * K + k0 + c1),
            (__attribute__((address_space(3))) void*)(Alds + 2048 + wid * 512), 16, 0, 0);
        __builtin_amdgcn_global_load_lds(
            (const __attribute__((address_space(1))) void*)(B + Bbase + (long)r0 * K + k0 + c0),
            (__attribute__((address_space(3))) void*)(Blds + wid * 512), 16, 0, 0);
        __builtin_amdgcn_global_load_lds(
            (const __attribute__((address_space(1))) void*)(B + Bbase + (long)r1 * K + k0 + c1),
            (__attribute__((address_space(3))) void*)(Blds + 2048 + wid * 512), 16, 0, 0);
        __syncthreads();

        bf16x8 af[4], bfr[4];
        #pragma unroll
        for (int m = 0; m < 4; m++)
            af[m] = *reinterpret_cast<const bf16x8*>(&Alds[(arow + m * 16) * 32 + koff]);
        #pragma unroll
        for (int n = 0; n < 4; n++)
            bfr[n] = *reinterpret_cast<const bf16x8*>(&Blds[(brow + n * 16) * 32 + koff]);
        #pragma unroll
        for (int m = 0; m < 4; m++)
            #pragma unroll
            for (int n = 0; n < 4; n++)
                acc[m][n] = __builtin_amdgcn_mfma_f32_16x16x32_bf16(af[m], bfr[n], acc[m][n], 0, 0, 0);
        __syncthreads();
    }

    const int crow0 = bm * 128 + wr * 64 + ((lane >> 4) << 2);
    const int ccol0 = bn * 128 + wc * 64 + (lane & 15);
    #pragma unroll
    for (int m = 0; m < 4; m++)
        #pragma unroll
        for (int j = 0; j < 4; j++) {
            const long r = crow0 + m * 16 + j;
            #pragma unroll
            for (int n = 0; n < 4; n++)
                C[r * N + ccol0 + n * 16] = f2bf(acc[m][n][j]);
        }
}

// ======== big BT-GEMM: 256x128 tile, BK=32, 8 waves of 64x64, 2 blocks/CU ========
// C[m][n] = sum_k A[m][k]*B[n][k] + bias[n] + resid[m][n], fp32 out.
// Occupancy design: acc[4][4]=64 AGPR + ~50 VGPR ≈ 115 unified regs/wave ->
// 4 waves/SIMD; LDS 3 x 24 KiB = 72 KiB -> 2 blocks/CU co-resident (epilogue
// of one block overlaps the K-loop of the other; 4 waves/SIMD hide LDS/MFMA
// latency).
// Swizzle (both-sides, rule 21): row stride 64 B = 4 x 16B slots; LDS slot
// (r,c) holds global k-chunk c ^ ((r>>1)&3).  Per 8-lane service group the
// read slots form a PERFECT permutation of the 8 slots in the 128-B window
// (rounds 3/4 were 2-deep per 8-lane group -> constant 1.26e7 conflicts).
// Pipeline: 3 buffers, stage tile kt+2 at tile kt (counted vmcnt(3) at top,
// 3 loads/tile/thread, ~2 tile-periods of HBM cover), ONE barrier per tile.
// Safety: per-tile lgkmcnt(0) before MFMA means every wave's reads of buf X
// are complete before it passes the next barrier; STAGE(kt+2) targets the
// buffer last read at kt-1, and is issued only after barrier(kt) -> no race.
__global__ __launch_bounds__(512, 4) void gemm_bt_256(
    const unsigned short* __restrict__ A, const unsigned short* __restrict__ B,
    float* __restrict__ C, const float* __restrict__ bias,
    const float* __restrict__ resid, int M, int N, int K)
{
    __shared__ __align__(16) char lds[73728];   // 3 x [A 16K | B 8K]

    const int nBN = N >> 7;             // 16
    int wg = blockIdx.x;
    const int cpx = gridDim.x >> 3;     // nwg % 8 == 0 (1024)
    wg = (wg & 7) * cpx + (wg >> 3);
    const int bm = wg / nBN, bn = wg % nBN;

    const int t = threadIdx.x;
    const int lane = t & 63, wid = t >> 6;
    const int wr = wid >> 1;            // 0..3 : wave row (64 rows)
    const int wcn = wid & 1;            // 0..1 : wave col (64 cols)

    // staging source (inverse-swizzled): thread t covers LDS slot (r_lo, t&3)
    const int r_lo = t >> 2, cch = t & 3;
    const int schunk = (cch ^ ((r_lo >> 1) & 3)) * 8;   // element offset of source chunk
    const unsigned short* sA0 = A + (long)(bm * 256 + r_lo) * K + schunk;
    const unsigned short* sA1 = sA0 + (long)128 * K;
    const unsigned short* sB0 = B + (long)(bn * 128 + r_lo) * K + schunk;

#define STAGE_AB(d) do { \
    const int dst_ = (d) * 24576 + wid * 1024; \
    __builtin_amdgcn_global_load_lds((const __attribute__((address_space(1))) void*)sA0, \
        (__attribute__((address_space(3))) void*)(lds + dst_), 16, 0, 0); \
    __builtin_amdgcn_global_load_lds((const __attribute__((address_space(1))) void*)sA1, \
        (__attribute__((address_space(3))) void*)(lds + dst_ + 8192), 16, 0, 0); \
    __builtin_amdgcn_global_load_lds((const __attribute__((address_space(1))) void*)sB0, \
        (__attribute__((address_space(3))) void*)(lds + dst_ + 16384), 16, 0, 0); \
    sA0 += 32; sA1 += 32; sB0 += 32; } while (0)

    // ds_read addressing (swizzled): row stride 64 B, slot = l4 ^ ((row>>1)&3)
    const int l15 = lane & 15, l4 = lane >> 4;
    const int koffb = ((l4 ^ ((l15 >> 1) & 3)) << 4);
    const int aRowB = (wr * 64 + l15) * 64 + koffb;            // + m*1024
    const int bRowB = 16384 + (wcn * 64 + l15) * 64 + koffb;   // + n*1024

    f32x4 acc[4][4];
    #pragma unroll
    for (int i = 0; i < 4; i++)
        #pragma unroll
        for (int j = 0; j < 4; j++) acc[i][j] = (f32x4){0.f, 0.f, 0.f, 0.f};

    const int nt = K >> 5;              // 64 tiles
    // prologue: stage tiles 0 (buf0) and 1 (buf1)
    STAGE_AB(0);
    STAGE_AB(1);

    int buf = 0;
    for (int kt = 0; kt < nt; ++kt) {
        // counted wait BEFORE barrier: my 3 loads for tile kt retired; the 3
        // for kt+1 stay in flight.  After the barrier, all waves' kt-loads
        // have retired -> buffer kt is fully resident.
        if (kt < nt - 1) asm volatile("s_waitcnt vmcnt(3)" ::: "memory");
        else             asm volatile("s_waitcnt vmcnt(0)" ::: "memory");
        __builtin_amdgcn_s_barrier();
        __builtin_amdgcn_sched_barrier(0);

        if (kt + 2 < nt) {
            const int nb2 = buf + 2 >= 3 ? buf - 1 : buf + 2;
            STAGE_AB(nb2);
        }

        const int bufb = buf * 24576;
        bf16x8 af[4], bfr[4];
        #pragma unroll
        for (int n = 0; n < 4; n++)
            bfr[n] = *reinterpret_cast<const bf16x8*>(lds + bufb + bRowB + n * 1024);
        #pragma unroll
        for (int m = 0; m < 4; m++)
            af[m] = *reinterpret_cast<const bf16x8*>(lds + bufb + aRowB + m * 1024);

        asm volatile("s_waitcnt lgkmcnt(0)" ::: "memory");
        __builtin_amdgcn_sched_barrier(0);
        __builtin_amdgcn_s_setprio(1);
        #pragma unroll
        for (int m = 0; m < 4; m++)
            #pragma unroll
            for (int n = 0; n < 4; n++)
                acc[m][n] = __builtin_amdgcn_mfma_f32_16x16x32_bf16(af[m], bfr[n], acc[m][n], 0, 0, 0);
        __builtin_amdgcn_s_setprio(0);

        buf = (buf + 1 == 3) ? 0 : buf + 1;
    }
#undef STAGE_AB

    // epilogue: C = acc + bias[col] + resid[row][col]
    const int crow0 = bm * 256 + wr * 64 + l4 * 4;
    const int ccol0 = bn * 128 + wcn * 64 + l15;
    #pragma unroll
    for (int m = 0; m < 4; m++)
        #pragma unroll
        for (int j = 0; j < 4; j++) {
            const long r = crow0 + m * 16 + j;
            float* crow = C + r * N;
            const float* rrow = resid + r * N;
            #pragma unroll
            for (int n = 0; n < 4; n++) {
                const int col = ccol0 + n * 16;
                crow[col] = acc[m][n][j] + bias[col] + rrow[col];
            }
        }
}

extern "C" void kernel_launch(void* const* d_in, const int* in_sizes, int n_in,
                              void* d_out, int out_size, void* d_ws, size_t ws_size,
                              hipStream_t stream) {
    // setup_inputs order: x, w_q, b_q, w_k, b_k, w_v, b_v, w_o, b_o, ln_gamma, ln_beta
    const float* x     = (const float*)d_in[0];
    const float* w_v   = (const float*)d_in[5];
    const float* b_v   = (const float*)d_in[6];
    const float* w_o   = (const float*)d_in[7];
    const float* b_o   = (const float*)d_in[8];
    const float* gamma = (const float*)d_in[9];
    const float* beta  = (const float*)d_in[10];
    float* out = (float*)d_out;

    char* ws = (char*)d_ws;
    unsigned short* h   = (unsigned short*)(ws);                              // 64 MiB
    unsigned short* wvT = (unsigned short*)(ws + 67108864L);                  // 8 MiB
    unsigned short* woB = (unsigned short*)(ws + 67108864L + 8388608L);       // 8 MiB
    unsigned short* Wc  = (unsigned short*)(ws + 67108864L + 2 * 8388608L);   // 8 MiB
    float*          b_c = (float*)(ws + 67108864L + 3 * 8388608L);            // 8 KiB

    // 1) h = LN(x) in bf16
    ln_kernel<<<N_BATCH, 256, 0, stream>>>(x, gamma, beta, h);
    // 2) wvT[k][j] = bf16(w_v[j][k])
    transpose_f32_to_bf16<<<(D_MODEL / 32) * (D_MODEL / 32), 256, 0, stream>>>(w_v, wvT, D_MODEL);
    // 3) woB = bf16(w_o)
    convert_bf16<<<(D_MODEL * (long)D_MODEL) / (256 * 8), 256, 0, stream>>>(w_o, woB, (long)D_MODEL * D_MODEL);
    // 4) b_c = w_o @ b_v + b_o (fp32)
    bias_combine<<<D_MODEL, 256, 0, stream>>>(w_o, b_v, b_o, b_c);
    // 5) Wc[n][k] = sum_j w_o[n][j] * w_v[j][k]
    gemm_bt_128<<<(D_MODEL / 128) * (D_MODEL / 128), 256, 0, stream>>>(
        woB, wvT, Wc, D_MODEL, D_MODEL, D_MODEL);
    // 6) out[b][n] = sum_k h[b][k] * Wc[n][k] + b_c[n] + x[b][n]
    gemm_bt_256<<<(N_BATCH / 256) * (D_MODEL / 128), 512, 0, stream>>>(
        h, Wc, out, b_c, x, N_BATCH, D_MODEL, D_MODEL);
}

// Round 7
// 242.672 us; speedup vs baseline: 1.0619x; 1.0619x over previous
//
#include <hip/hip_runtime.h>
#include <hip/hip_bf16.h>
#include <cstdint>

#define D_MODEL 2048
#define N_BATCH 16384

typedef __attribute__((ext_vector_type(8))) __bf16 bf16x8;
typedef __attribute__((ext_vector_type(4))) float f32x4;

__device__ __forceinline__ unsigned short f2bf(float f) {
    unsigned int u = __builtin_bit_cast(unsigned int, f);
    u += 0x7fffu + ((u >> 16) & 1u);
    return (unsigned short)(u >> 16);
}

// ---------------- LayerNorm: x fp32 [B][D] -> h bf16 [B][D] ----------------
__global__ __launch_bounds__(256) void ln_kernel(
    const float* __restrict__ x, const float* __restrict__ gamma,
    const float* __restrict__ beta, unsigned short* __restrict__ h)
{
    const int row = blockIdx.x;
    const int t = threadIdx.x;
    const float4* x4 = reinterpret_cast<const float4*>(x + (long)row * D_MODEL);
    float4 a = x4[t];
    float4 b = x4[256 + t];
    float s  = a.x + a.y + a.z + a.w + b.x + b.y + b.z + b.w;
    float ss = a.x*a.x + a.y*a.y + a.z*a.z + a.w*a.w
             + b.x*b.x + b.y*b.y + b.z*b.z + b.w*b.w;
    #pragma unroll
    for (int off = 32; off; off >>= 1) {
        s  += __shfl_xor(s, off);
        ss += __shfl_xor(ss, off);
    }
    __shared__ float red[8];
    const int lane = t & 63, wid = t >> 6;
    if (lane == 0) { red[wid*2] = s; red[wid*2+1] = ss; }
    __syncthreads();
    s  = red[0] + red[2] + red[4] + red[6];
    ss = red[1] + red[3] + red[5] + red[7];
    const float mean = s * (1.0f / D_MODEL);
    const float var  = ss * (1.0f / D_MODEL) - mean * mean;
    const float inv  = rsqrtf(var + 1e-5f);

    const float4* g4  = reinterpret_cast<const float4*>(gamma);
    const float4* be4 = reinterpret_cast<const float4*>(beta);
    ushort4* h4 = reinterpret_cast<ushort4*>(h + (long)row * D_MODEL);
    {
        float4 g = g4[t], be = be4[t];
        ushort4 o;
        o.x = f2bf((a.x - mean) * inv * g.x + be.x);
        o.y = f2bf((a.y - mean) * inv * g.y + be.y);
        o.z = f2bf((a.z - mean) * inv * g.z + be.z);
        o.w = f2bf((a.w - mean) * inv * g.w + be.w);
        h4[t] = o;
    }
    {
        float4 g = g4[256 + t], be = be4[256 + t];
        ushort4 o;
        o.x = f2bf((b.x - mean) * inv * g.x + be.x);
        o.y = f2bf((b.y - mean) * inv * g.y + be.y);
        o.z = f2bf((b.z - mean) * inv * g.z + be.z);
        o.w = f2bf((b.w - mean) * inv * g.w + be.w);
        h4[256 + t] = o;
    }
}

// ------------- transpose + convert: out[k][j] = bf16(in[j][k]) -------------
__global__ __launch_bounds__(256) void transpose_f32_to_bf16(
    const float* __restrict__ in, unsigned short* __restrict__ out, int Dm)
{
    __shared__ float tile[32][33];
    const int nb = Dm >> 5;
    const int k0 = (blockIdx.x % nb) * 32;
    const int j0 = (blockIdx.x / nb) * 32;
    const int tx = threadIdx.x & 31, ty0 = threadIdx.x >> 5;
    #pragma unroll
    for (int i = 0; i < 32; i += 8) {
        int j = ty0 + i;
        tile[j][tx] = in[(long)(j0 + j) * Dm + k0 + tx];
    }
    __syncthreads();
    #pragma unroll
    for (int i = 0; i < 32; i += 8) {
        int kk = ty0 + i;
        out[(long)(k0 + kk) * Dm + j0 + tx] = f2bf(tile[tx][kk]);
    }
}

// ---------------- elementwise convert fp32 -> bf16 ----------------
__global__ __launch_bounds__(256) void convert_bf16(
    const float* __restrict__ in, unsigned short* __restrict__ out, long n)
{
    long i = ((long)blockIdx.x * 256 + threadIdx.x) * 8;
    if (i >= n) return;
    const float4* in4 = reinterpret_cast<const float4*>(in + i);
    float4 a = in4[0], b = in4[1];
    union { unsigned short u[8]; uint4 v; } o;
    o.u[0] = f2bf(a.x); o.u[1] = f2bf(a.y); o.u[2] = f2bf(a.z); o.u[3] = f2bf(a.w);
    o.u[4] = f2bf(b.x); o.u[5] = f2bf(b.y); o.u[6] = f2bf(b.z); o.u[7] = f2bf(b.w);
    *reinterpret_cast<uint4*>(out + i) = o.v;
}

// ---------------- b_c[n] = b_o[n] + sum_j w_o[n][j]*b_v[j] (fp32) ----------------
__global__ __launch_bounds__(256) void bias_combine(
    const float* __restrict__ w_o, const float* __restrict__ b_v,
    const float* __restrict__ b_o, float* __restrict__ b_c)
{
    const int n = blockIdx.x;
    const int t = threadIdx.x;
    const float4* w4 = reinterpret_cast<const float4*>(w_o + (long)n * D_MODEL);
    const float4* v4 = reinterpret_cast<const float4*>(b_v);
    float4 a = w4[t], b = w4[256 + t], va = v4[t], vb = v4[256 + t];
    float s = a.x*va.x + a.y*va.y + a.z*va.z + a.w*va.w
            + b.x*vb.x + b.y*vb.y + b.z*vb.z + b.w*vb.w;
    #pragma unroll
    for (int off = 32; off; off >>= 1) s += __shfl_xor(s, off);
    __shared__ float red[4];
    const int lane = t & 63, wid = t >> 6;
    if (lane == 0) red[wid] = s;
    __syncthreads();
    if (t == 0) b_c[n] = red[0] + red[1] + red[2] + red[3] + b_o[n];
}

// ---------------- small BT-GEMM (128x128 tile, m97 structure), bf16 out ----------------
__global__ __launch_bounds__(256, 2) void gemm_bt_128(
    const unsigned short* __restrict__ A, const unsigned short* __restrict__ B,
    unsigned short* __restrict__ C, int M, int N, int K)
{
    const int nBN = N >> 7;
    int wg = blockIdx.x;
    const int nwg = gridDim.x;
    const int cpx = nwg >> 3;
    wg = (wg & 7) * cpx + (wg >> 3);
    const int bm = wg / nBN, bn = wg % nBN;

    const int t = threadIdx.x;
    const int lane = t & 63, wid = t >> 6;
    const int wr = wid >> 1, wc = wid & 1;

    __shared__ __align__(16) unsigned short Alds[128 * 32];
    __shared__ __align__(16) unsigned short Blds[128 * 32];

    f32x4 acc[4][4];
    #pragma unroll
    for (int i = 0; i < 4; i++)
        #pragma unroll
        for (int j = 0; j < 4; j++) acc[i][j] = (f32x4){0.f, 0.f, 0.f, 0.f};

    const long Abase = (long)bm * 128 * K;
    const long Bbase = (long)bn * 128 * K;
    const int ci0 = wid * 64 + lane;
    const int ci1 = 256 + ci0;
    const int r0 = ci0 >> 2, c0 = (ci0 & 3) * 8;
    const int r1 = ci1 >> 2, c1 = (ci1 & 3) * 8;

    const int arow = wr * 64 + (lane & 15);
    const int brow = wc * 64 + (lane & 15);
    const int koff = (lane >> 4) * 8;

    for (int k0 = 0; k0 < K; k0 += 32) {
        __builtin_amdgcn_global_load_lds(
            (const __attribute__((address_space(1))) void*)(A + Abase + (long)r0 * K + k0 + c0),
            (__attribute__((address_space(3))) void*)(Alds + wid * 512), 16, 0, 0);
        __builtin_amdgcn_global_load_lds(
            (const __attribute__((address_space(1))) void*)(A + Abase + (long)r1 * K + k0 + c1),
            (__attribute__((address_space(3))) void*)(Alds + 2048 + wid * 512), 16, 0, 0);
        __builtin_amdgcn_global_load_lds(
            (const __attribute__((address_space(1))) void*)(B + Bbase + (long)r0 * K + k0 + c0),
            (__attribute__((address_space(3))) void*)(Blds + wid * 512), 16, 0, 0);
        __builtin_amdgcn_global_load_lds(
            (const __attribute__((address_space(1))) void*)(B + Bbase + (long)r1 * K + k0 + c1),
            (__attribute__((address_space(3))) void*)(Blds + 2048 + wid * 512), 16, 0, 0);
        __syncthreads();

        bf16x8 af[4], bfr[4];
        #pragma unroll
        for (int m = 0; m < 4; m++)
            af[m] = *reinterpret_cast<const bf16x8*>(&Alds[(arow + m * 16) * 32 + koff]);
        #pragma unroll
        for (int n = 0; n < 4; n++)
            bfr[n] = *reinterpret_cast<const bf16x8*>(&Blds[(brow + n * 16) * 32 + koff]);
        #pragma unroll
        for (int m = 0; m < 4; m++)
            #pragma unroll
            for (int n = 0; n < 4; n++)
                acc[m][n] = __builtin_amdgcn_mfma_f32_16x16x32_bf16(af[m], bfr[n], acc[m][n], 0, 0, 0);
        __syncthreads();
    }

    const int crow0 = bm * 128 + wr * 64 + ((lane >> 4) << 2);
    const int ccol0 = bn * 128 + wc * 64 + (lane & 15);
    #pragma unroll
    for (int m = 0; m < 4; m++)
        #pragma unroll
        for (int j = 0; j < 4; j++) {
            const long r = crow0 + m * 16 + j;
            #pragma unroll
            for (int n = 0; n < 4; n++)
                C[r * N + ccol0 + n * 16] = f2bf(acc[m][n][j]);
        }
}

// ======== big BT-GEMM: 256x256 8-phase template (race-fixed ledger) ========
// C[m][n] = sum_k A[m][k]*B[n][k] + bias[n] + resid[m][n], fp32 out.
// BK=64, 2 K-tiles/iter (buf0=even, buf1=odd). 8 waves = 2M x 4N (128x64 out,
// acc[8][4]). LDS 128 KiB = 2 buf x {A-h0,A-h1,B-h0,B-h1} 16 KB slots.
// KEY (round-6 race fix): RD_A selects its A half-slot by wr, RD_B by wc>>1;
// so BOTH A halves are read at ph1+ph3 (ph5+ph7 for buf1) and BOTH B halves
// at ph1+ph2 (ph5+ph6).  Legal stage windows per slot:
//   buf0-B >= ph3 ; buf0-A >= ph4 ; buf1-B >= ph7 ; buf1-A >= ph8 (or ph1/2
//   of next iter, since buf1-A is untouched until ph5).
// Ledger (iter i): ph1: A1h0(K-tile 2i+1)  ph2: A1h1(2i+1)
//                  ph3: B0h0(2i+2)         ph4: B0h1(2i+2)  + vmcnt(4)
//                  ph5: A0h0(2i+2)         ph6: A0h1(2i+2)
//                  ph7: B1h0(2i+3)         ph8: B1h1(2i+3)  + vmcnt(4)
// vmcnt(4)@ph4 retires everything through ph2 (buf1 resident for ph5; ph3/4
// in flight); vmcnt(4)@ph8 retires through ph6 (buf0 resident for next ph1;
// ph7/8 in flight). Waits sit BEFORE the closing barrier (wait-then-barrier-
// then-read publishes all waves' stages). Last iter: ph4 drains to 0.
// Swizzle (r2-proven, 0 conflicts): slot s of row r holds k-chunk s^(r&7);
// linear gload_lds dst + inverse-swizzled global src (rule 21).
#define GLL(src, dst) __builtin_amdgcn_global_load_lds( \
    (const __attribute__((address_space(1))) void*)(src), \
    (__attribute__((address_space(3))) void*)(dst), 16, 0, 0)
#define WAITV4() do { asm volatile("s_waitcnt vmcnt(4)" ::: "memory"); \
                      __builtin_amdgcn_sched_barrier(0); } while (0)
#define WAITV0() do { asm volatile("s_waitcnt vmcnt(0)" ::: "memory"); \
                      __builtin_amdgcn_sched_barrier(0); } while (0)

__global__ __launch_bounds__(512, 2) void gemm_bt_8ph(
    const unsigned short* __restrict__ A, const unsigned short* __restrict__ B,
    float* __restrict__ C, const float* __restrict__ bias,
    const float* __restrict__ resid, int M, int N, int K)
{
    __shared__ __align__(16) char ldsb[131072];

    const int nBN = N >> 8;             // 8
    int wg = blockIdx.x;
    const int cpx = gridDim.x >> 3;     // 512 % 8 == 0
    wg = (wg & 7) * cpx + (wg >> 3);
    const int bm = wg / nBN, bn = wg % nBN;

    const int t = threadIdx.x;
    const int lane = t & 63, wid = t >> 6;
    const int wr = wid >> 2;            // 0..1
    const int wc = wid & 3;             // 0..3

    // ---- staging addressing (inverse-swizzled source) ----
    const long Kl = K;
    const int tr = t >> 3;                                  // row 0..63
    const int c8 = ((t & 7) ^ (tr & 7)) * 8;                // source k-chunk
    const unsigned short* As = A + (long)(bm * 256 + tr) * Kl + c8;
    const unsigned short* Bs = B + (long)(bn * 256 + tr) * Kl + c8;

#define ST_A(buf, half, kcol) do { \
    const unsigned short* s_ = As + (half) * 128 * Kl + (kcol); \
    char* d_ = ldsb + (buf) * 65536 + (half) * 16384 + t * 16; \
    GLL(s_, d_); GLL(s_ + 64 * Kl, d_ + 8192); } while (0)
#define ST_B(buf, half, kcol) do { \
    const unsigned short* s_ = Bs + (half) * 128 * Kl + (kcol); \
    char* d_ = ldsb + (buf) * 65536 + 32768 + (half) * 16384 + t * 16; \
    GLL(s_, d_); GLL(s_ + 64 * Kl, d_ + 8192); } while (0)

    // ---- ds_read addressing (swizzled) ----
    const int l15 = lane & 15, l4 = lane >> 4;
    const int swz0 = ((l4)     ^ (l15 & 7)) << 4;           // kk=0
    const int swz1 = ((4 + l4) ^ (l15 & 7)) << 4;           // kk=1
    const int aOff = wr * 16384 + l15 * 128;
    const int bOff = 32768 + (wc >> 1) * 16384 + ((wc & 1) * 64 + l15) * 128;

#define LDV(off) (*reinterpret_cast<const bf16x8*>(ldsb + (off)))
#define RD_A(buf, mh) do { _Pragma("unroll") for (int mi = 0; mi < 4; ++mi) { \
    af[mi][0] = LDV((buf) * 65536 + aOff + ((mh) * 4 + mi) * 2048 + swz0); \
    af[mi][1] = LDV((buf) * 65536 + aOff + ((mh) * 4 + mi) * 2048 + swz1); } } while (0)
#define RD_B0(buf) do { _Pragma("unroll") for (int nj = 0; nj < 2; ++nj) { \
    b0[nj][0] = LDV((buf) * 65536 + bOff + nj * 2048 + swz0); \
    b0[nj][1] = LDV((buf) * 65536 + bOff + nj * 2048 + swz1); } } while (0)
#define RD_B1(buf) do { _Pragma("unroll") for (int nj = 0; nj < 2; ++nj) { \
    b1[nj][0] = LDV((buf) * 65536 + bOff + (2 + nj) * 2048 + swz0); \
    b1[nj][1] = LDV((buf) * 65536 + bOff + (2 + nj) * 2048 + swz1); } } while (0)

#define MMQ(mh, nh, BQ) do { \
    __builtin_amdgcn_s_barrier(); \
    asm volatile("s_waitcnt lgkmcnt(0)" ::: "memory"); \
    __builtin_amdgcn_sched_barrier(0); \
    __builtin_amdgcn_s_setprio(1); \
    _Pragma("unroll") for (int mi = 0; mi < 4; ++mi) \
    _Pragma("unroll") for (int nj = 0; nj < 2; ++nj) \
    _Pragma("unroll") for (int kk = 0; kk < 2; ++kk) \
        acc[(mh) * 4 + mi][(nh) * 2 + nj] = __builtin_amdgcn_mfma_f32_16x16x32_bf16( \
            af[mi][kk], BQ[nj][kk], acc[(mh) * 4 + mi][(nh) * 2 + nj], 0, 0, 0); \
    __builtin_amdgcn_s_setprio(0); } while (0)
#define ENDP() __builtin_amdgcn_s_barrier()

    bf16x8 af[4][2], b0[2][2], b1[2][2];
    f32x4 acc[8][4];
    #pragma unroll
    for (int i = 0; i < 8; i++)
        #pragma unroll
        for (int j = 0; j < 4; j++) acc[i][j] = (f32x4){0.f, 0.f, 0.f, 0.f};

    const int NI = K >> 7;              // 16 iterations, 2 K-tiles each

    // prologue: buf0 <- K-tile 0 (4 halves, 8 loads); buf1-B <- K-tile 1
    // (4 loads).  buf1-A(K-tile 1) is staged at ph1/ph2 of iter 0.
    ST_A(0, 0, 0); ST_A(0, 1, 0); ST_B(0, 0, 0); ST_B(0, 1, 0);
    ST_B(1, 0, 64); ST_B(1, 1, 64);
    WAITV4();                           // buf0's 8 retired; buf1-B in flight
    __builtin_amdgcn_s_barrier();

    for (int i = 0; i < NI; ++i) {
        const int kcA1 = (i << 7) + 64;          // K-tile 2i+1 (buf1-A, this iter)
        const int kcN0 = (i << 7) + 128;         // K-tile 2i+2 (buf0, next iter)
        const int kcN1 = (i << 7) + 192;         // K-tile 2i+3 (buf1, next iter)
        const bool more = (i + 1 < NI);

        // ph1: Q(0,0) buf0 ; stage buf1-A h0 (needed ph5)
        RD_A(0, 0); RD_B0(0);
        ST_A(1, 0, kcA1);
        MMQ(0, 0, b0); ENDP();
        // ph2: Q(0,1) ; stage buf1-A h1
        RD_B1(0);
        ST_A(1, 1, kcA1);
        MMQ(0, 1, b1); ENDP();
        // ph3: Q(1,0) ; stage buf0-B h0 (B halves free after ph2)
        RD_A(0, 1);
        if (more) ST_B(0, 0, kcN0);
        MMQ(1, 0, b0); ENDP();
        // ph4: Q(1,1) ; stage buf0-B h1 ; wait buf1 resident (through ph2)
        if (more) ST_B(0, 1, kcN0);
        MMQ(1, 1, b1);
        if (more) { WAITV4(); } else { WAITV0(); }
        ENDP();
        // ph5: Q(0,0) buf1 ; stage buf0-A h0 (A halves free after ph3)
        RD_A(1, 0); RD_B0(1);
        if (more) ST_A(0, 0, kcN0);
        MMQ(0, 0, b0); ENDP();
        // ph6: Q(0,1) ; stage buf0-A h1
        RD_B1(1);
        if (more) ST_A(0, 1, kcN0);
        MMQ(0, 1, b1); ENDP();
        // ph7: Q(1,0) ; stage buf1-B h0 (free after ph6)
        RD_A(1, 1);
        if (more) ST_B(1, 0, kcN1);
        MMQ(1, 0, b0); ENDP();
        // ph8: Q(1,1) ; stage buf1-B h1 ; wait buf0 resident (through ph6)
        if (more) ST_B(1, 1, kcN1);
        MMQ(1, 1, b1);
        if (more) { WAITV4(); }
        ENDP();
    }
#undef ST_A
#undef ST_B
#undef RD_A
#undef RD_B0
#undef RD_B1
#undef MMQ
#undef ENDP
#undef LDV

    // epilogue: C = acc + bias[col] + resid[row][col]
    const int crow0 = bm * 256 + wr * 128 + l4 * 4;
    const int ccol0 = bn * 256 + wc * 64 + l15;
    #pragma unroll
    for (int m = 0; m < 8; m++)
        #pragma unroll
        for (int j = 0; j < 4; j++) {
            const long r = crow0 + m * 16 + j;
            float* crow = C + r * N;
            const float* rrow = resid + r * N;
            #pragma unroll
            for (int n = 0; n < 4; n++) {
                const int col = ccol0 + n * 16;
                crow[col] = acc[m][n][j] + bias[col] + rrow[col];
            }
        }
}

extern "C" void kernel_launch(void* const* d_in, const int* in_sizes, int n_in,
                              void* d_out, int out_size, void* d_ws, size_t ws_size,
                              hipStream_t stream) {
    // setup_inputs order: x, w_q, b_q, w_k, b_k, w_v, b_v, w_o, b_o, ln_gamma, ln_beta
    const float* x     = (const float*)d_in[0];
    const float* w_v   = (const float*)d_in[5];
    const float* b_v   = (const float*)d_in[6];
    const float* w_o   = (const float*)d_in[7];
    const float* b_o   = (const float*)d_in[8];
    const float* gamma = (const float*)d_in[9];
    const float* beta  = (const float*)d_in[10];
    float* out = (float*)d_out;

    char* ws = (char*)d_ws;
    unsigned short* h   = (unsigned short*)(ws);                              // 64 MiB
    unsigned short* wvT = (unsigned short*)(ws + 67108864L);                  // 8 MiB
    unsigned short* woB = (unsigned short*)(ws + 67108864L + 8388608L);       // 8 MiB
    unsigned short* Wc  = (unsigned short*)(ws + 67108864L + 2 * 8388608L);   // 8 MiB
    float*          b_c = (float*)(ws + 67108864L + 3 * 8388608L);            // 8 KiB

    // 1) h = LN(x) in bf16
    ln_kernel<<<N_BATCH, 256, 0, stream>>>(x, gamma, beta, h);
    // 2) wvT[k][j] = bf16(w_v[j][k])
    transpose_f32_to_bf16<<<(D_MODEL / 32) * (D_MODEL / 32), 256, 0, stream>>>(w_v, wvT, D_MODEL);
    // 3) woB = bf16(w_o)
    convert_bf16<<<(D_MODEL * (long)D_MODEL) / (256 * 8), 256, 0, stream>>>(w_o, woB, (long)D_MODEL * D_MODEL);
    // 4) b_c = w_o @ b_v + b_o (fp32)
    bias_combine<<<D_MODEL, 256, 0, stream>>>(w_o, b_v, b_o, b_c);
    // 5) Wc[n][k] = sum_j w_o[n][j] * w_v[j][k]
    gemm_bt_128<<<(D_MODEL / 128) * (D_MODEL / 128), 256, 0, stream>>>(
        woB, wvT, Wc, D_MODEL, D_MODEL, D_MODEL);
    // 6) out[b][n] = sum_k h[b][k] * Wc[n][k] + b_c[n] + x[b][n]
    gemm_bt_8ph<<<(N_BATCH / 256) * (D_MODEL / 256), 512, 0, stream>>>(
        h, Wc, out, b_c, x, N_BATCH, D_MODEL, D_MODEL);
}

// Round 8
// 232.732 us; speedup vs baseline: 1.1072x; 1.0427x over previous
//
#include <hip/hip_runtime.h>
#include <hip/hip_bf16.h>
#include <cstdint>

#define D_MODEL 2048
#define N_BATCH 16384

typedef __attribute__((ext_vector_type(8))) __bf16 bf16x8;
typedef __attribute__((ext_vector_type(4))) float f32x4;

__device__ __forceinline__ unsigned short f2bf(float f) {
    unsigned int u = __builtin_bit_cast(unsigned int, f);
    u += 0x7fffu + ((u >> 16) & 1u);
    return (unsigned short)(u >> 16);
}

// ============ K1: fused prep = transpose(w_v) || convert(w_o) || bias ============
// blocks [0,4096): wvT[k][j] = bf16(w_v[j][k])       (32x32 tiles, 64x64 grid)
// blocks [4096,6144): woB = bf16(w_o)                (2048 blocks x 2048 elems)
// blocks [6144,8192): b_c[n] = b_o[n] + w_o[n,:].b_v (2048 rows)
__global__ __launch_bounds__(256) void prep_kernel(
    const float* __restrict__ w_v, const float* __restrict__ w_o,
    const float* __restrict__ b_v, const float* __restrict__ b_o,
    unsigned short* __restrict__ wvT, unsigned short* __restrict__ woB,
    float* __restrict__ b_c)
{
    __shared__ float tile[32][33];
    const int b = blockIdx.x;
    const int t = threadIdx.x;
    if (b < 4096) {
        const int nb = 64;
        const int k0 = (b % nb) * 32;
        const int j0 = (b / nb) * 32;
        const int tx = t & 31, ty0 = t >> 5;
        #pragma unroll
        for (int i = 0; i < 32; i += 8) {
            int j = ty0 + i;
            tile[j][tx] = w_v[(long)(j0 + j) * D_MODEL + k0 + tx];
        }
        __syncthreads();
        #pragma unroll
        for (int i = 0; i < 32; i += 8) {
            int kk = ty0 + i;
            wvT[(long)(k0 + kk) * D_MODEL + j0 + tx] = f2bf(tile[tx][kk]);
        }
    } else if (b < 6144) {
        long i = ((long)(b - 4096) * 256 + t) * 8;
        const float4* in4 = reinterpret_cast<const float4*>(w_o + i);
        float4 a = in4[0], bb = in4[1];
        union { unsigned short u[8]; uint4 v; } o;
        o.u[0] = f2bf(a.x); o.u[1] = f2bf(a.y); o.u[2] = f2bf(a.z); o.u[3] = f2bf(a.w);
        o.u[4] = f2bf(bb.x); o.u[5] = f2bf(bb.y); o.u[6] = f2bf(bb.z); o.u[7] = f2bf(bb.w);
        *reinterpret_cast<uint4*>(woB + i) = o.v;
    } else {
        const int n = b - 6144;
        const float4* w4 = reinterpret_cast<const float4*>(w_o + (long)n * D_MODEL);
        const float4* v4 = reinterpret_cast<const float4*>(b_v);
        float4 a = w4[t], bb = w4[256 + t], va = v4[t], vb = v4[256 + t];
        float s = a.x*va.x + a.y*va.y + a.z*va.z + a.w*va.w
                + bb.x*vb.x + bb.y*vb.y + bb.z*vb.z + bb.w*vb.w;
        #pragma unroll
        for (int off = 32; off; off >>= 1) s += __shfl_xor(s, off);
        float* red = &tile[0][0];
        const int lane = t & 63, wid = t >> 6;
        if (lane == 0) red[wid] = s;
        __syncthreads();
        if (t == 0) b_c[n] = red[0] + red[1] + red[2] + red[3] + b_o[n];
    }
}

// ============ K2: fused Wc-GEMM (128-tile m97) || LayerNorm ============
// blocks [0,256): Wc[n][k] = sum_j woB[n][j] * wvT[k][j]  (2048^3, bf16 out)
// blocks [256, 16640): h[row] = bf16(LN(x[row]))
__global__ __launch_bounds__(256) void lnwc_kernel(
    const unsigned short* __restrict__ A, const unsigned short* __restrict__ B,
    unsigned short* __restrict__ C,
    const float* __restrict__ x, const float* __restrict__ gamma,
    const float* __restrict__ beta, unsigned short* __restrict__ h)
{
    __shared__ __align__(16) unsigned short Alds[128 * 32];
    __shared__ __align__(16) unsigned short Blds[128 * 32];
    const int t = threadIdx.x;

    if (blockIdx.x < 256) {
        const int K = D_MODEL, N = D_MODEL;
        int wg = blockIdx.x;
        wg = (wg & 7) * 32 + (wg >> 3);         // XCD swizzle, cpx = 32
        const int bm = wg >> 4, bn = wg & 15;

        const int lane = t & 63, wid = t >> 6;
        const int wr = wid >> 1, wc = wid & 1;

        f32x4 acc[4][4];
        #pragma unroll
        for (int i = 0; i < 4; i++)
            #pragma unroll
            for (int j = 0; j < 4; j++) acc[i][j] = (f32x4){0.f, 0.f, 0.f, 0.f};

        const long Abase = (long)bm * 128 * K;
        const long Bbase = (long)bn * 128 * K;
        const int ci0 = wid * 64 + lane;
        const int ci1 = 256 + ci0;
        const int r0 = ci0 >> 2, c0 = (ci0 & 3) * 8;
        const int r1 = ci1 >> 2, c1 = (ci1 & 3) * 8;

        const int arow = wr * 64 + (lane & 15);
        const int brow = wc * 64 + (lane & 15);
        const int koff = (lane >> 4) * 8;

        for (int k0 = 0; k0 < K; k0 += 32) {
            __builtin_amdgcn_global_load_lds(
                (const __attribute__((address_space(1))) void*)(A + Abase + (long)r0 * K + k0 + c0),
                (__attribute__((address_space(3))) void*)(Alds + wid * 512), 16, 0, 0);
            __builtin_amdgcn_global_load_lds(
                (const __attribute__((address_space(1))) void*)(A + Abase + (long)r1 * K + k0 + c1),
                (__attribute__((address_space(3))) void*)(Alds + 2048 + wid * 512), 16, 0, 0);
            __builtin_amdgcn_global_load_lds(
                (const __attribute__((address_space(1))) void*)(B + Bbase + (long)r0 * K + k0 + c0),
                (__attribute__((address_space(3))) void*)(Blds + wid * 512), 16, 0, 0);
            __builtin_amdgcn_global_load_lds(
                (const __attribute__((address_space(1))) void*)(B + Bbase + (long)r1 * K + k0 + c1),
                (__attribute__((address_space(3))) void*)(Blds + 2048 + wid * 512), 16, 0, 0);
            __syncthreads();

            bf16x8 af[4], bfr[4];
            #pragma unroll
            for (int m = 0; m < 4; m++)
                af[m] = *reinterpret_cast<const bf16x8*>(&Alds[(arow + m * 16) * 32 + koff]);
            #pragma unroll
            for (int n = 0; n < 4; n++)
                bfr[n] = *reinterpret_cast<const bf16x8*>(&Blds[(brow + n * 16) * 32 + koff]);
            #pragma unroll
            for (int m = 0; m < 4; m++)
                #pragma unroll
                for (int n = 0; n < 4; n++)
                    acc[m][n] = __builtin_amdgcn_mfma_f32_16x16x32_bf16(af[m], bfr[n], acc[m][n], 0, 0, 0);
            __syncthreads();
        }

        const int crow0 = bm * 128 + wr * 64 + ((lane >> 4) << 2);
        const int ccol0 = bn * 128 + wc * 64 + (lane & 15);
        #pragma unroll
        for (int m = 0; m < 4; m++)
            #pragma unroll
            for (int j = 0; j < 4; j++) {
                const long r = crow0 + m * 16 + j;
                #pragma unroll
                for (int n = 0; n < 4; n++)
                    C[r * N + ccol0 + n * 16] = f2bf(acc[m][n][j]);
            }
    } else {
        const int row = blockIdx.x - 256;
        const float4* x4 = reinterpret_cast<const float4*>(x + (long)row * D_MODEL);
        float4 a = x4[t];
        float4 b = x4[256 + t];
        float s  = a.x + a.y + a.z + a.w + b.x + b.y + b.z + b.w;
        float ss = a.x*a.x + a.y*a.y + a.z*a.z + a.w*a.w
                 + b.x*b.x + b.y*b.y + b.z*b.z + b.w*b.w;
        #pragma unroll
        for (int off = 32; off; off >>= 1) {
            s  += __shfl_xor(s, off);
            ss += __shfl_xor(ss, off);
        }
        float* red = reinterpret_cast<float*>(Alds);
        const int lane = t & 63, wid = t >> 6;
        if (lane == 0) { red[wid*2] = s; red[wid*2+1] = ss; }
        __syncthreads();
        s  = red[0] + red[2] + red[4] + red[6];
        ss = red[1] + red[3] + red[5] + red[7];
        const float mean = s * (1.0f / D_MODEL);
        const float var  = ss * (1.0f / D_MODEL) - mean * mean;
        const float inv  = rsqrtf(var + 1e-5f);

        const float4* g4  = reinterpret_cast<const float4*>(gamma);
        const float4* be4 = reinterpret_cast<const float4*>(beta);
        ushort4* h4 = reinterpret_cast<ushort4*>(h + (long)row * D_MODEL);
        {
            float4 g = g4[t], be = be4[t];
            ushort4 o;
            o.x = f2bf((a.x - mean) * inv * g.x + be.x);
            o.y = f2bf((a.y - mean) * inv * g.y + be.y);
            o.z = f2bf((a.z - mean) * inv * g.z + be.z);
            o.w = f2bf((a.w - mean) * inv * g.w + be.w);
            h4[t] = o;
        }
        {
            float4 g = g4[256 + t], be = be4[256 + t];
            ushort4 o;
            o.x = f2bf((b.x - mean) * inv * g.x + be.x);
            o.y = f2bf((b.y - mean) * inv * g.y + be.y);
            o.z = f2bf((b.z - mean) * inv * g.z + be.z);
            o.w = f2bf((b.w - mean) * inv * g.w + be.w);
            h4[256 + t] = o;
        }
    }
}

// ======== K3: big BT-GEMM, 256x256 8-phase, rebalanced ledger + kk-outer ========
// C[m][n] = sum_k A[m][k]*B[n][k] + bias[n] + resid[m][n], fp32 out.
// BK=64, 2 K-tiles/iter (buf0=even, buf1=odd). 8 waves = 2M x 4N (128x64 out).
// Read facts: A halves read ph1+ph3 (buf0) / ph5+ph7 (buf1); B halves read
// ph1+ph2 / ph5+ph6.  Slot-free times: buf0-B: ph3; buf0-A: ph4; buf1-B: ph7;
// buf1-A: ph8.
// Ledger (iter i; tiles 2i,2i+1 consumed; stages for 2i+1..2i+3):
//   ph1: A1h1(2i+1)   ph2: B1h1(2i+1)   ph3: B0h0(2i+2)   ph4: A0h0(2i+2) +W4
//   ph5: A0h1(2i+2)   ph6: B0h1(2i+2)   ph7: B1h0(2i+3)   ph8: A1h0(2i+3) +W4
// A (HBM, ~900cy) covers: 3-4 phases; B (L2-resident Wc) covers: 2-5 phases.
// W4@ph4 retires through ph2 (buf1 resident; ph3/ph4 = 4 in flight).
// W4@ph8 retires through ph6 (buf0 resident; ph7/ph8 = 4 in flight).
// Prologue: buf0 x4 + B1h0 + A1h0 (12 loads), W4 -> buf0's 8 retired.
// Last iter: ph1/ph2 still stage (this iter's buf1); ph3+ skipped; ph4 drains.
// kk-OUTER MFMA: the two writes to the same acc are 7 ops apart (no dep stall).
// Swizzle (r2-proven 0-conflict): slot s of row r holds k-chunk s^(r&7).
#define GLL(src, dst) __builtin_amdgcn_global_load_lds( \
    (const __attribute__((address_space(1))) void*)(src), \
    (__attribute__((address_space(3))) void*)(dst), 16, 0, 0)
#define WAITV4() do { asm volatile("s_waitcnt vmcnt(4)" ::: "memory"); \
                      __builtin_amdgcn_sched_barrier(0); } while (0)
#define WAITV0() do { asm volatile("s_waitcnt vmcnt(0)" ::: "memory"); \
                      __builtin_amdgcn_sched_barrier(0); } while (0)

__global__ __launch_bounds__(512, 2) void gemm_bt_8ph(
    const unsigned short* __restrict__ A, const unsigned short* __restrict__ B,
    float* __restrict__ C, const float* __restrict__ bias,
    const float* __restrict__ resid, int M, int N, int K)
{
    __shared__ __align__(16) char ldsb[131072];

    const int nBN = N >> 8;             // 8
    int wg = blockIdx.x;
    const int cpx = gridDim.x >> 3;     // 512 % 8 == 0
    wg = (wg & 7) * cpx + (wg >> 3);
    const int bm = wg / nBN, bn = wg % nBN;

    const int t = threadIdx.x;
    const int lane = t & 63, wid = t >> 6;
    const int wr = wid >> 2;            // 0..1
    const int wc = wid & 3;             // 0..3

    // ---- staging addressing (inverse-swizzled source) ----
    const long Kl = K;
    const int tr = t >> 3;                                  // row 0..63
    const int c8 = ((t & 7) ^ (tr & 7)) * 8;                // source k-chunk
    const unsigned short* As = A + (long)(bm * 256 + tr) * Kl + c8;
    const unsigned short* Bs = B + (long)(bn * 256 + tr) * Kl + c8;

#define ST_A(buf, half, kcol) do { \
    const unsigned short* s_ = As + (half) * 128 * Kl + (kcol); \
    char* d_ = ldsb + (buf) * 65536 + (half) * 16384 + t * 16; \
    GLL(s_, d_); GLL(s_ + 64 * Kl, d_ + 8192); } while (0)
#define ST_B(buf, half, kcol) do { \
    const unsigned short* s_ = Bs + (half) * 128 * Kl + (kcol); \
    char* d_ = ldsb + (buf) * 65536 + 32768 + (half) * 16384 + t * 16; \
    GLL(s_, d_); GLL(s_ + 64 * Kl, d_ + 8192); } while (0)

    // ---- ds_read addressing (swizzled) ----
    const int l15 = lane & 15, l4 = lane >> 4;
    const int swz0 = ((l4)     ^ (l15 & 7)) << 4;           // kk=0
    const int swz1 = ((4 + l4) ^ (l15 & 7)) << 4;           // kk=1
    const int aOff = wr * 16384 + l15 * 128;
    const int bOff = 32768 + (wc >> 1) * 16384 + ((wc & 1) * 64 + l15) * 128;

#define LDV(off) (*reinterpret_cast<const bf16x8*>(ldsb + (off)))
#define RD_A(buf, mh) do { _Pragma("unroll") for (int mi = 0; mi < 4; ++mi) { \
    af[mi][0] = LDV((buf) * 65536 + aOff + ((mh) * 4 + mi) * 2048 + swz0); \
    af[mi][1] = LDV((buf) * 65536 + aOff + ((mh) * 4 + mi) * 2048 + swz1); } } while (0)
#define RD_B0(buf) do { _Pragma("unroll") for (int nj = 0; nj < 2; ++nj) { \
    b0[nj][0] = LDV((buf) * 65536 + bOff + nj * 2048 + swz0); \
    b0[nj][1] = LDV((buf) * 65536 + bOff + nj * 2048 + swz1); } } while (0)
#define RD_B1(buf) do { _Pragma("unroll") for (int nj = 0; nj < 2; ++nj) { \
    b1[nj][0] = LDV((buf) * 65536 + bOff + (2 + nj) * 2048 + swz0); \
    b1[nj][1] = LDV((buf) * 65536 + bOff + (2 + nj) * 2048 + swz1); } } while (0)

#define MMQ(mh, nh, BQ) do { \
    __builtin_amdgcn_s_barrier(); \
    asm volatile("s_waitcnt lgkmcnt(0)" ::: "memory"); \
    __builtin_amdgcn_sched_barrier(0); \
    __builtin_amdgcn_s_setprio(1); \
    _Pragma("unroll") for (int kk = 0; kk < 2; ++kk) \
    _Pragma("unroll") for (int mi = 0; mi < 4; ++mi) \
    _Pragma("unroll") for (int nj = 0; nj < 2; ++nj) \
        acc[(mh) * 4 + mi][(nh) * 2 + nj] = __builtin_amdgcn_mfma_f32_16x16x32_bf16( \
            af[mi][kk], BQ[nj][kk], acc[(mh) * 4 + mi][(nh) * 2 + nj], 0, 0, 0); \
    __builtin_amdgcn_s_setprio(0); } while (0)
#define ENDP() __builtin_amdgcn_s_barrier()

    bf16x8 af[4][2], b0[2][2], b1[2][2];
    f32x4 acc[8][4];
    #pragma unroll
    for (int i = 0; i < 8; i++)
        #pragma unroll
        for (int j = 0; j < 4; j++) acc[i][j] = (f32x4){0.f, 0.f, 0.f, 0.f};

    const int NI = K >> 7;              // 16 iterations, 2 K-tiles each

    // prologue: buf0 (4 halves) + B1h0 + A1h0 of K-tile 1 (12 loads)
    ST_A(0, 0, 0); ST_A(0, 1, 0); ST_B(0, 0, 0); ST_B(0, 1, 0);
    ST_B(1, 0, 64); ST_A(1, 0, 64);
    WAITV4();                           // buf0's 8 retired; tile-1 h0s in flight
    __builtin_amdgcn_s_barrier();

    for (int i = 0; i < NI; ++i) {
        const int kcA1 = (i << 7) + 64;          // K-tile 2i+1 (buf1, this iter)
        const int kcN0 = (i << 7) + 128;         // K-tile 2i+2 (buf0, next iter)
        const int kcN1 = (i << 7) + 192;         // K-tile 2i+3 (buf1, next iter)
        const bool more = (i + 1 < NI);

        // ph1: Q(0,0) buf0 ; stage buf1-A h1 (h0 staged prev ph8/prologue)
        RD_A(0, 0); RD_B0(0);
        ST_A(1, 1, kcA1);
        MMQ(0, 0, b0); ENDP();
        // ph2: Q(0,1) ; stage buf1-B h1
        RD_B1(0);
        ST_B(1, 1, kcA1);
        MMQ(0, 1, b1); ENDP();
        // ph3: Q(1,0) ; stage buf0-B h0 (next pair) — B free after ph2
        RD_A(0, 1);
        if (more) ST_B(0, 0, kcN0);
        MMQ(1, 0, b0); ENDP();
        // ph4: Q(1,1) ; stage buf0-A h0 (A free after ph3) ; wait buf1 resident
        if (more) ST_A(0, 0, kcN0);
        MMQ(1, 1, b1);
        if (more) { WAITV4(); } else { WAITV0(); }
        ENDP();
        // ph5: Q(0,0) buf1 ; stage buf0-A h1
        RD_A(1, 0); RD_B0(1);
        if (more) ST_A(0, 1, kcN0);
        MMQ(0, 0, b0); ENDP();
        // ph6: Q(0,1) ; stage buf0-B h1
        RD_B1(1);
        if (more) ST_B(0, 1, kcN0);
        MMQ(0, 1, b1); ENDP();
        // ph7: Q(1,0) ; stage buf1-B h0 (tile 2i+3) — buf1-B free after ph6
        RD_A(1, 1);
        if (more) ST_B(1, 0, kcN1);
        MMQ(1, 0, b0); ENDP();
        // ph8: Q(1,1) ; stage buf1-A h0 (tile 2i+3) — buf1-A free after ph7
        if (more) ST_A(1, 0, kcN1);
        MMQ(1, 1, b1);
        if (more) { WAITV4(); }
        ENDP();
    }
#undef ST_A
#undef ST_B
#undef RD_A
#undef RD_B0
#undef RD_B1
#undef MMQ
#undef ENDP
#undef LDV

    // epilogue: C = acc + bias[col] + resid[row][col]
    const int crow0 = bm * 256 + wr * 128 + l4 * 4;
    const int ccol0 = bn * 256 + wc * 64 + l15;
    #pragma unroll
    for (int m = 0; m < 8; m++)
        #pragma unroll
        for (int j = 0; j < 4; j++) {
            const long r = crow0 + m * 16 + j;
            float* crow = C + r * N;
            const float* rrow = resid + r * N;
            #pragma unroll
            for (int n = 0; n < 4; n++) {
                const int col = ccol0 + n * 16;
                crow[col] = acc[m][n][j] + bias[col] + rrow[col];
            }
        }
}

extern "C" void kernel_launch(void* const* d_in, const int* in_sizes, int n_in,
                              void* d_out, int out_size, void* d_ws, size_t ws_size,
                              hipStream_t stream) {
    // setup_inputs order: x, w_q, b_q, w_k, b_k, w_v, b_v, w_o, b_o, ln_gamma, ln_beta
    const float* x     = (const float*)d_in[0];
    const float* w_v   = (const float*)d_in[5];
    const float* b_v   = (const float*)d_in[6];
    const float* w_o   = (const float*)d_in[7];
    const float* b_o   = (const float*)d_in[8];
    const float* gamma = (const float*)d_in[9];
    const float* beta  = (const float*)d_in[10];
    float* out = (float*)d_out;

    char* ws = (char*)d_ws;
    unsigned short* h   = (unsigned short*)(ws);                              // 64 MiB
    unsigned short* wvT = (unsigned short*)(ws + 67108864L);                  // 8 MiB
    unsigned short* woB = (unsigned short*)(ws + 67108864L + 8388608L);       // 8 MiB
    unsigned short* Wc  = (unsigned short*)(ws + 67108864L + 2 * 8388608L);   // 8 MiB
    float*          b_c = (float*)(ws + 67108864L + 3 * 8388608L);            // 8 KiB

    // K1: transpose(w_v) || convert(w_o) || bias-combine
    prep_kernel<<<8192, 256, 0, stream>>>(w_v, w_o, b_v, b_o, wvT, woB, b_c);
    // K2: Wc = woB . wvT^T (blocks 0-255) || h = LN(x) (blocks 256+)
    lnwc_kernel<<<256 + N_BATCH, 256, 0, stream>>>(woB, wvT, Wc, x, gamma, beta, h);
    // K3: out = h . Wc^T + b_c + x
    gemm_bt_8ph<<<(N_BATCH / 256) * (D_MODEL / 256), 512, 0, stream>>>(
        h, Wc, out, b_c, x, N_BATCH, D_MODEL, D_MODEL);
}

// Round 9
// 228.559 us; speedup vs baseline: 1.1274x; 1.0183x over previous
//
#include <hip/hip_runtime.h>
#include <hip/hip_bf16.h>
#include <cstdint>

#define D_MODEL 2048
#define N_BATCH 16384

typedef __attribute__((ext_vector_type(8))) __bf16 bf16x8;
typedef __attribute__((ext_vector_type(4))) float f32x4;

__device__ __forceinline__ unsigned short f2bf(float f) {
    unsigned int u = __builtin_bit_cast(unsigned int, f);
    u += 0x7fffu + ((u >> 16) & 1u);
    return (unsigned short)(u >> 16);
}

// ============ K1: fused prep = transpose(w_v) || convert(w_o) || bias ============
__global__ __launch_bounds__(256) void prep_kernel(
    const float* __restrict__ w_v, const float* __restrict__ w_o,
    const float* __restrict__ b_v, const float* __restrict__ b_o,
    unsigned short* __restrict__ wvT, unsigned short* __restrict__ woB,
    float* __restrict__ b_c)
{
    __shared__ float tile[32][33];
    const int b = blockIdx.x;
    const int t = threadIdx.x;
    if (b < 4096) {
        const int nb = 64;
        const int k0 = (b % nb) * 32;
        const int j0 = (b / nb) * 32;
        const int tx = t & 31, ty0 = t >> 5;
        #pragma unroll
        for (int i = 0; i < 32; i += 8) {
            int j = ty0 + i;
            tile[j][tx] = w_v[(long)(j0 + j) * D_MODEL + k0 + tx];
        }
        __syncthreads();
        #pragma unroll
        for (int i = 0; i < 32; i += 8) {
            int kk = ty0 + i;
            wvT[(long)(k0 + kk) * D_MODEL + j0 + tx] = f2bf(tile[tx][kk]);
        }
    } else if (b < 6144) {
        long i = ((long)(b - 4096) * 256 + t) * 8;
        const float4* in4 = reinterpret_cast<const float4*>(w_o + i);
        float4 a = in4[0], bb = in4[1];
        union { unsigned short u[8]; uint4 v; } o;
        o.u[0] = f2bf(a.x); o.u[1] = f2bf(a.y); o.u[2] = f2bf(a.z); o.u[3] = f2bf(a.w);
        o.u[4] = f2bf(bb.x); o.u[5] = f2bf(bb.y); o.u[6] = f2bf(bb.z); o.u[7] = f2bf(bb.w);
        *reinterpret_cast<uint4*>(woB + i) = o.v;
    } else {
        const int n = b - 6144;
        const float4* w4 = reinterpret_cast<const float4*>(w_o + (long)n * D_MODEL);
        const float4* v4 = reinterpret_cast<const float4*>(b_v);
        float4 a = w4[t], bb = w4[256 + t], va = v4[t], vb = v4[256 + t];
        float s = a.x*va.x + a.y*va.y + a.z*va.z + a.w*va.w
                + bb.x*vb.x + bb.y*vb.y + bb.z*vb.z + bb.w*vb.w;
        #pragma unroll
        for (int off = 32; off; off >>= 1) s += __shfl_xor(s, off);
        float* red = &tile[0][0];
        const int lane = t & 63, wid = t >> 6;
        if (lane == 0) red[wid] = s;
        __syncthreads();
        if (t == 0) b_c[n] = red[0] + red[1] + red[2] + red[3] + b_o[n];
    }
}

// ============ K2: fused Wc-GEMM (128-tile m97) || LayerNorm ============
__global__ __launch_bounds__(256) void lnwc_kernel(
    const unsigned short* __restrict__ A, const unsigned short* __restrict__ B,
    unsigned short* __restrict__ C,
    const float* __restrict__ x, const float* __restrict__ gamma,
    const float* __restrict__ beta, unsigned short* __restrict__ h)
{
    __shared__ __align__(16) unsigned short Alds[128 * 32];
    __shared__ __align__(16) unsigned short Blds[128 * 32];
    const int t = threadIdx.x;

    if (blockIdx.x < 256) {
        const int K = D_MODEL, N = D_MODEL;
        int wg = blockIdx.x;
        wg = (wg & 7) * 32 + (wg >> 3);         // XCD swizzle, cpx = 32
        const int bm = wg >> 4, bn = wg & 15;

        const int lane = t & 63, wid = t >> 6;
        const int wr = wid >> 1, wc = wid & 1;

        f32x4 acc[4][4];
        #pragma unroll
        for (int i = 0; i < 4; i++)
            #pragma unroll
            for (int j = 0; j < 4; j++) acc[i][j] = (f32x4){0.f, 0.f, 0.f, 0.f};

        const long Abase = (long)bm * 128 * K;
        const long Bbase = (long)bn * 128 * K;
        const int ci0 = wid * 64 + lane;
        const int ci1 = 256 + ci0;
        const int r0 = ci0 >> 2, c0 = (ci0 & 3) * 8;
        const int r1 = ci1 >> 2, c1 = (ci1 & 3) * 8;

        const int arow = wr * 64 + (lane & 15);
        const int brow = wc * 64 + (lane & 15);
        const int koff = (lane >> 4) * 8;

        for (int k0 = 0; k0 < K; k0 += 32) {
            __builtin_amdgcn_global_load_lds(
                (const __attribute__((address_space(1))) void*)(A + Abase + (long)r0 * K + k0 + c0),
                (__attribute__((address_space(3))) void*)(Alds + wid * 512), 16, 0, 0);
            __builtin_amdgcn_global_load_lds(
                (const __attribute__((address_space(1))) void*)(A + Abase + (long)r1 * K + k0 + c1),
                (__attribute__((address_space(3))) void*)(Alds + 2048 + wid * 512), 16, 0, 0);
            __builtin_amdgcn_global_load_lds(
                (const __attribute__((address_space(1))) void*)(B + Bbase + (long)r0 * K + k0 + c0),
                (__attribute__((address_space(3))) void*)(Blds + wid * 512), 16, 0, 0);
            __builtin_amdgcn_global_load_lds(
                (const __attribute__((address_space(1))) void*)(B + Bbase + (long)r1 * K + k0 + c1),
                (__attribute__((address_space(3))) void*)(Blds + 2048 + wid * 512), 16, 0, 0);
            __syncthreads();

            bf16x8 af[4], bfr[4];
            #pragma unroll
            for (int m = 0; m < 4; m++)
                af[m] = *reinterpret_cast<const bf16x8*>(&Alds[(arow + m * 16) * 32 + koff]);
            #pragma unroll
            for (int n = 0; n < 4; n++)
                bfr[n] = *reinterpret_cast<const bf16x8*>(&Blds[(brow + n * 16) * 32 + koff]);
            #pragma unroll
            for (int m = 0; m < 4; m++)
                #pragma unroll
                for (int n = 0; n < 4; n++)
                    acc[m][n] = __builtin_amdgcn_mfma_f32_16x16x32_bf16(af[m], bfr[n], acc[m][n], 0, 0, 0);
            __syncthreads();
        }

        const int crow0 = bm * 128 + wr * 64 + ((lane >> 4) << 2);
        const int ccol0 = bn * 128 + wc * 64 + (lane & 15);
        #pragma unroll
        for (int m = 0; m < 4; m++)
            #pragma unroll
            for (int j = 0; j < 4; j++) {
                const long r = crow0 + m * 16 + j;
                #pragma unroll
                for (int n = 0; n < 4; n++)
                    C[r * N + ccol0 + n * 16] = f2bf(acc[m][n][j]);
            }
    } else {
        const int row = blockIdx.x - 256;
        const float4* x4 = reinterpret_cast<const float4*>(x + (long)row * D_MODEL);
        float4 a = x4[t];
        float4 b = x4[256 + t];
        float s  = a.x + a.y + a.z + a.w + b.x + b.y + b.z + b.w;
        float ss = a.x*a.x + a.y*a.y + a.z*a.z + a.w*a.w
                 + b.x*b.x + b.y*b.y + b.z*b.z + b.w*b.w;
        #pragma unroll
        for (int off = 32; off; off >>= 1) {
            s  += __shfl_xor(s, off);
            ss += __shfl_xor(ss, off);
        }
        float* red = reinterpret_cast<float*>(Alds);
        const int lane = t & 63, wid = t >> 6;
        if (lane == 0) { red[wid*2] = s; red[wid*2+1] = ss; }
        __syncthreads();
        s  = red[0] + red[2] + red[4] + red[6];
        ss = red[1] + red[3] + red[5] + red[7];
        const float mean = s * (1.0f / D_MODEL);
        const float var  = ss * (1.0f / D_MODEL) - mean * mean;
        const float inv  = rsqrtf(var + 1e-5f);

        const float4* g4  = reinterpret_cast<const float4*>(gamma);
        const float4* be4 = reinterpret_cast<const float4*>(beta);
        ushort4* h4 = reinterpret_cast<ushort4*>(h + (long)row * D_MODEL);
        {
            float4 g = g4[t], be = be4[t];
            ushort4 o;
            o.x = f2bf((a.x - mean) * inv * g.x + be.x);
            o.y = f2bf((a.y - mean) * inv * g.y + be.y);
            o.z = f2bf((a.z - mean) * inv * g.z + be.z);
            o.w = f2bf((a.w - mean) * inv * g.w + be.w);
            h4[t] = o;
        }
        {
            float4 g = g4[256 + t], be = be4[256 + t];
            ushort4 o;
            o.x = f2bf((b.x - mean) * inv * g.x + be.x);
            o.y = f2bf((b.y - mean) * inv * g.y + be.y);
            o.z = f2bf((b.z - mean) * inv * g.z + be.z);
            o.w = f2bf((b.w - mean) * inv * g.w + be.w);
            h4[256 + t] = o;
        }
    }
}

// ======== K3: big BT-GEMM, 256x256 8-phase, RELAXED intra-phase schedule ========
// C[m][n] = sum_k A[m][k]*B[n][k] + bias[n] + resid[m][n], fp32 out.
// Same proven ledger/swizzle/vmcnt as r7/r8.  CHANGE (r9): one barrier per
// phase (the phase-END barrier = the WAR publisher); no lgkmcnt(0) pin, no
// sched_barrier — ds_reads are plain C++ loads, the compiler emits counted
// lgkmcnt(N) and interleaves reads with MFMA (m97 evidence), so the LDS port
// runs DURING the MFMA burst instead of strictly before it.  Reads batched
// k0-then-k1 so MFMA kk=0 can start while kk=1 reads drain.
// Ledger (iter i; tiles 2i,2i+1 consumed; stages for 2i+1..2i+3):
//   ph1: A1h1(2i+1)   ph2: B1h1(2i+1)   ph3: B0h0(2i+2)   ph4: A0h0(2i+2) +W4
//   ph5: A0h1(2i+2)   ph6: B0h1(2i+2)   ph7: B1h0(2i+3)   ph8: A1h0(2i+3) +W4
// Stage slots free: buf0-B>=ph3, buf0-A>=ph4, buf1-B>=ph7, buf1-A>=ph8 (or
// ph1/2 next iter).  W4@ph4 retires through ph2 (buf1 resident for ph5);
// W4@ph8 retires through ph6 (buf0 resident for next ph1); waits sit before
// the phase-end barrier.  Last iter: ph4 drains vmcnt(0).
// Swizzle (r2-proven 0-conflict): slot s of row r holds k-chunk s^(r&7);
// linear gload_lds dst + inverse-swizzled global src (rule 21).
#define GLL(src, dst) __builtin_amdgcn_global_load_lds( \
    (const __attribute__((address_space(1))) void*)(src), \
    (__attribute__((address_space(3))) void*)(dst), 16, 0, 0)
#define WAITV4() do { asm volatile("s_waitcnt vmcnt(4)" ::: "memory"); \
                      __builtin_amdgcn_sched_barrier(0); } while (0)
#define WAITV0() do { asm volatile("s_waitcnt vmcnt(0)" ::: "memory"); \
                      __builtin_amdgcn_sched_barrier(0); } while (0)

__global__ __launch_bounds__(512, 2) void gemm_bt_8ph(
    const unsigned short* __restrict__ A, const unsigned short* __restrict__ B,
    float* __restrict__ C, const float* __restrict__ bias,
    const float* __restrict__ resid, int M, int N, int K)
{
    __shared__ __align__(16) char ldsb[131072];

    const int nBN = N >> 8;             // 8
    int wg = blockIdx.x;
    const int cpx = gridDim.x >> 3;     // 512 % 8 == 0
    wg = (wg & 7) * cpx + (wg >> 3);
    const int bm = wg / nBN, bn = wg % nBN;

    const int t = threadIdx.x;
    const int lane = t & 63, wid = t >> 6;
    const int wr = wid >> 2;            // 0..1
    const int wc = wid & 3;             // 0..3

    // ---- staging addressing (inverse-swizzled source) ----
    const long Kl = K;
    const int tr = t >> 3;                                  // row 0..63
    const int c8 = ((t & 7) ^ (tr & 7)) * 8;                // source k-chunk
    const unsigned short* As = A + (long)(bm * 256 + tr) * Kl + c8;
    const unsigned short* Bs = B + (long)(bn * 256 + tr) * Kl + c8;

#define ST_A(buf, half, kcol) do { \
    const unsigned short* s_ = As + (half) * 128 * Kl + (kcol); \
    char* d_ = ldsb + (buf) * 65536 + (half) * 16384 + t * 16; \
    GLL(s_, d_); GLL(s_ + 64 * Kl, d_ + 8192); } while (0)
#define ST_B(buf, half, kcol) do { \
    const unsigned short* s_ = Bs + (half) * 128 * Kl + (kcol); \
    char* d_ = ldsb + (buf) * 65536 + 32768 + (half) * 16384 + t * 16; \
    GLL(s_, d_); GLL(s_ + 64 * Kl, d_ + 8192); } while (0)

    // ---- ds_read addressing (swizzled) ----
    const int l15 = lane & 15, l4 = lane >> 4;
    const int swz0 = ((l4)     ^ (l15 & 7)) << 4;           // kk=0
    const int swz1 = ((4 + l4) ^ (l15 & 7)) << 4;           // kk=1
    const int aOff = wr * 16384 + l15 * 128;
    const int bOff = 32768 + (wc >> 1) * 16384 + ((wc & 1) * 64 + l15) * 128;

#define LDV(off) (*reinterpret_cast<const bf16x8*>(ldsb + (off)))
// reads batched k0-first, then k1 (lets MFMA kk=0 start while k1 drains)
#define RD_A(buf, mh) do { \
    _Pragma("unroll") for (int mi = 0; mi < 4; ++mi) \
        af[mi][0] = LDV((buf) * 65536 + aOff + ((mh) * 4 + mi) * 2048 + swz0); \
    _Pragma("unroll") for (int mi = 0; mi < 4; ++mi) \
        af[mi][1] = LDV((buf) * 65536 + aOff + ((mh) * 4 + mi) * 2048 + swz1); } while (0)
#define RD_B0(buf) do { \
    _Pragma("unroll") for (int nj = 0; nj < 2; ++nj) \
        b0[nj][0] = LDV((buf) * 65536 + bOff + nj * 2048 + swz0); \
    _Pragma("unroll") for (int nj = 0; nj < 2; ++nj) \
        b0[nj][1] = LDV((buf) * 65536 + bOff + nj * 2048 + swz1); } while (0)
#define RD_B1(buf) do { \
    _Pragma("unroll") for (int nj = 0; nj < 2; ++nj) \
        b1[nj][0] = LDV((buf) * 65536 + bOff + (2 + nj) * 2048 + swz0); \
    _Pragma("unroll") for (int nj = 0; nj < 2; ++nj) \
        b1[nj][1] = LDV((buf) * 65536 + bOff + (2 + nj) * 2048 + swz1); } while (0)

// relaxed: no pre-barrier, no lgkmcnt(0) pin — compiler inserts counted
// lgkm waits per true dependency and interleaves reads with MFMA.
#define MMQ(mh, nh, BQ) do { \
    __builtin_amdgcn_s_setprio(1); \
    _Pragma("unroll") for (int kk = 0; kk < 2; ++kk) \
    _Pragma("unroll") for (int mi = 0; mi < 4; ++mi) \
    _Pragma("unroll") for (int nj = 0; nj < 2; ++nj) \
        acc[(mh) * 4 + mi][(nh) * 2 + nj] = __builtin_amdgcn_mfma_f32_16x16x32_bf16( \
            af[mi][kk], BQ[nj][kk], acc[(mh) * 4 + mi][(nh) * 2 + nj], 0, 0, 0); \
    __builtin_amdgcn_s_setprio(0); } while (0)
#define ENDP() __builtin_amdgcn_s_barrier()

    bf16x8 af[4][2], b0[2][2], b1[2][2];
    f32x4 acc[8][4];
    #pragma unroll
    for (int i = 0; i < 8; i++)
        #pragma unroll
        for (int j = 0; j < 4; j++) acc[i][j] = (f32x4){0.f, 0.f, 0.f, 0.f};

    const int NI = K >> 7;              // 16 iterations, 2 K-tiles each

    // prologue: buf0 (4 halves) + B1h0 + A1h0 of K-tile 1 (12 loads)
    ST_A(0, 0, 0); ST_A(0, 1, 0); ST_B(0, 0, 0); ST_B(0, 1, 0);
    ST_B(1, 0, 64); ST_A(1, 0, 64);
    WAITV4();                           // buf0's 8 retired; tile-1 h0s in flight
    __builtin_amdgcn_s_barrier();

    for (int i = 0; i < NI; ++i) {
        const int kcA1 = (i << 7) + 64;          // K-tile 2i+1 (buf1, this iter)
        const int kcN0 = (i << 7) + 128;         // K-tile 2i+2 (buf0, next iter)
        const int kcN1 = (i << 7) + 192;         // K-tile 2i+3 (buf1, next iter)
        const bool more = (i + 1 < NI);

        // ph1: Q(0,0) buf0 ; stage buf1-A h1
        RD_A(0, 0); RD_B0(0);
        ST_A(1, 1, kcA1);
        MMQ(0, 0, b0); ENDP();
        // ph2: Q(0,1) ; stage buf1-B h1
        RD_B1(0);
        ST_B(1, 1, kcA1);
        MMQ(0, 1, b1); ENDP();
        // ph3: Q(1,0) ; stage buf0-B h0 (next pair)
        RD_A(0, 1);
        if (more) ST_B(0, 0, kcN0);
        MMQ(1, 0, b0); ENDP();
        // ph4: Q(1,1) ; stage buf0-A h0 ; wait buf1 resident
        if (more) ST_A(0, 0, kcN0);
        MMQ(1, 1, b1);
        if (more) { WAITV4(); } else { WAITV0(); }
        ENDP();
        // ph5: Q(0,0) buf1 ; stage buf0-A h1
        RD_A(1, 0); RD_B0(1);
        if (more) ST_A(0, 1, kcN0);
        MMQ(0, 0, b0); ENDP();
        // ph6: Q(0,1) ; stage buf0-B h1
        RD_B1(1);
        if (more) ST_B(0, 1, kcN0);
        MMQ(0, 1, b1); ENDP();
        // ph7: Q(1,0) ; stage buf1-B h0 (tile 2i+3)
        RD_A(1, 1);
        if (more) ST_B(1, 0, kcN1);
        MMQ(1, 0, b0); ENDP();
        // ph8: Q(1,1) ; stage buf1-A h0 (tile 2i+3) ; wait buf0 resident
        if (more) ST_A(1, 0, kcN1);
        MMQ(1, 1, b1);
        if (more) { WAITV4(); }
        ENDP();
    }
#undef ST_A
#undef ST_B
#undef RD_A
#undef RD_B0
#undef RD_B1
#undef MMQ
#undef ENDP
#undef LDV

    // epilogue: C = acc + bias[col] + resid[row][col]
    const int crow0 = bm * 256 + wr * 128 + l4 * 4;
    const int ccol0 = bn * 256 + wc * 64 + l15;
    #pragma unroll
    for (int m = 0; m < 8; m++)
        #pragma unroll
        for (int j = 0; j < 4; j++) {
            const long r = crow0 + m * 16 + j;
            float* crow = C + r * N;
            const float* rrow = resid + r * N;
            #pragma unroll
            for (int n = 0; n < 4; n++) {
                const int col = ccol0 + n * 16;
                crow[col] = acc[m][n][j] + bias[col] + rrow[col];
            }
        }
}

extern "C" void kernel_launch(void* const* d_in, const int* in_sizes, int n_in,
                              void* d_out, int out_size, void* d_ws, size_t ws_size,
                              hipStream_t stream) {
    // setup_inputs order: x, w_q, b_q, w_k, b_k, w_v, b_v, w_o, b_o, ln_gamma, ln_beta
    const float* x     = (const float*)d_in[0];
    const float* w_v   = (const float*)d_in[5];
    const float* b_v   = (const float*)d_in[6];
    const float* w_o   = (const float*)d_in[7];
    const float* b_o   = (const float*)d_in[8];
    const float* gamma = (const float*)d_in[9];
    const float* beta  = (const float*)d_in[10];
    float* out = (float*)d_out;

    char* ws = (char*)d_ws;
    unsigned short* h   = (unsigned short*)(ws);                              // 64 MiB
    unsigned short* wvT = (unsigned short*)(ws + 67108864L);                  // 8 MiB
    unsigned short* woB = (unsigned short*)(ws + 67108864L + 8388608L);       // 8 MiB
    unsigned short* Wc  = (unsigned short*)(ws + 67108864L + 2 * 8388608L);   // 8 MiB
    float*          b_c = (float*)(ws + 67108864L + 3 * 8388608L);            // 8 KiB

    // K1: transpose(w_v) || convert(w_o) || bias-combine
    prep_kernel<<<8192, 256, 0, stream>>>(w_v, w_o, b_v, b_o, wvT, woB, b_c);
    // K2: Wc = woB . wvT^T (blocks 0-255) || h = LN(x) (blocks 256+)
    lnwc_kernel<<<256 + N_BATCH, 256, 0, stream>>>(woB, wvT, Wc, x, gamma, beta, h);
    // K3: out = h . Wc^T + b_c + x
    gemm_bt_8ph<<<(N_BATCH / 256) * (D_MODEL / 256), 512, 0, stream>>>(
        h, Wc, out, b_c, x, N_BATCH, D_MODEL, D_MODEL);
}

// Round 10
// 220.902 us; speedup vs baseline: 1.1665x; 1.0347x over previous
//
#include <hip/hip_runtime.h>
#include <hip/hip_bf16.h>
#include <cstdint>

#define D_MODEL 2048
#define N_BATCH 16384

typedef __attribute__((ext_vector_type(8))) __bf16 bf16x8;
typedef __attribute__((ext_vector_type(4))) float f32x4;

__device__ __forceinline__ unsigned short f2bf(float f) {
    unsigned int u = __builtin_bit_cast(unsigned int, f);
    u += 0x7fffu + ((u >> 16) & 1u);
    return (unsigned short)(u >> 16);
}

// ============ K1: fused prep = transpose(w_v) || convert(w_o) || bias ============
__global__ __launch_bounds__(256) void prep_kernel(
    const float* __restrict__ w_v, const float* __restrict__ w_o,
    const float* __restrict__ b_v, const float* __restrict__ b_o,
    unsigned short* __restrict__ wvT, unsigned short* __restrict__ woB,
    float* __restrict__ b_c)
{
    __shared__ float tile[32][33];
    const int b = blockIdx.x;
    const int t = threadIdx.x;
    if (b < 4096) {
        const int nb = 64;
        const int k0 = (b % nb) * 32;
        const int j0 = (b / nb) * 32;
        const int tx = t & 31, ty0 = t >> 5;
        #pragma unroll
        for (int i = 0; i < 32; i += 8) {
            int j = ty0 + i;
            tile[j][tx] = w_v[(long)(j0 + j) * D_MODEL + k0 + tx];
        }
        __syncthreads();
        #pragma unroll
        for (int i = 0; i < 32; i += 8) {
            int kk = ty0 + i;
            wvT[(long)(k0 + kk) * D_MODEL + j0 + tx] = f2bf(tile[tx][kk]);
        }
    } else if (b < 6144) {
        long i = ((long)(b - 4096) * 256 + t) * 8;
        const float4* in4 = reinterpret_cast<const float4*>(w_o + i);
        float4 a = in4[0], bb = in4[1];
        union { unsigned short u[8]; uint4 v; } o;
        o.u[0] = f2bf(a.x); o.u[1] = f2bf(a.y); o.u[2] = f2bf(a.z); o.u[3] = f2bf(a.w);
        o.u[4] = f2bf(bb.x); o.u[5] = f2bf(bb.y); o.u[6] = f2bf(bb.z); o.u[7] = f2bf(bb.w);
        *reinterpret_cast<uint4*>(woB + i) = o.v;
    } else {
        const int n = b - 6144;
        const float4* w4 = reinterpret_cast<const float4*>(w_o + (long)n * D_MODEL);
        const float4* v4 = reinterpret_cast<const float4*>(b_v);
        float4 a = w4[t], bb = w4[256 + t], va = v4[t], vb = v4[256 + t];
        float s = a.x*va.x + a.y*va.y + a.z*va.z + a.w*va.w
                + bb.x*vb.x + bb.y*vb.y + bb.z*vb.z + bb.w*vb.w;
        #pragma unroll
        for (int off = 32; off; off >>= 1) s += __shfl_xor(s, off);
        float* red = &tile[0][0];
        const int lane = t & 63, wid = t >> 6;
        if (lane == 0) red[wid] = s;
        __syncthreads();
        if (t == 0) b_c[n] = red[0] + red[1] + red[2] + red[3] + b_o[n];
    }
}

// ============ K2: fused Wc-GEMM (128-tile m97) || LayerNorm ============
__global__ __launch_bounds__(256) void lnwc_kernel(
    const unsigned short* __restrict__ A, const unsigned short* __restrict__ B,
    unsigned short* __restrict__ C,
    const float* __restrict__ x, const float* __restrict__ gamma,
    const float* __restrict__ beta, unsigned short* __restrict__ h)
{
    __shared__ __align__(16) unsigned short Alds[128 * 32];
    __shared__ __align__(16) unsigned short Blds[128 * 32];
    const int t = threadIdx.x;

    if (blockIdx.x < 256) {
        const int K = D_MODEL, N = D_MODEL;
        int wg = blockIdx.x;
        wg = (wg & 7) * 32 + (wg >> 3);         // XCD swizzle, cpx = 32
        const int bm = wg >> 4, bn = wg & 15;

        const int lane = t & 63, wid = t >> 6;
        const int wr = wid >> 1, wc = wid & 1;

        f32x4 acc[4][4];
        #pragma unroll
        for (int i = 0; i < 4; i++)
            #pragma unroll
            for (int j = 0; j < 4; j++) acc[i][j] = (f32x4){0.f, 0.f, 0.f, 0.f};

        const long Abase = (long)bm * 128 * K;
        const long Bbase = (long)bn * 128 * K;
        const int ci0 = wid * 64 + lane;
        const int ci1 = 256 + ci0;
        const int r0 = ci0 >> 2, c0 = (ci0 & 3) * 8;
        const int r1 = ci1 >> 2, c1 = (ci1 & 3) * 8;

        const int arow = wr * 64 + (lane & 15);
        const int brow = wc * 64 + (lane & 15);
        const int koff = (lane >> 4) * 8;

        for (int k0 = 0; k0 < K; k0 += 32) {
            __builtin_amdgcn_global_load_lds(
                (const __attribute__((address_space(1))) void*)(A + Abase + (long)r0 * K + k0 + c0),
                (__attribute__((address_space(3))) void*)(Alds + wid * 512), 16, 0, 0);
            __builtin_amdgcn_global_load_lds(
                (const __attribute__((address_space(1))) void*)(A + Abase + (long)r1 * K + k0 + c1),
                (__attribute__((address_space(3))) void*)(Alds + 2048 + wid * 512), 16, 0, 0);
            __builtin_amdgcn_global_load_lds(
                (const __attribute__((address_space(1))) void*)(B + Bbase + (long)r0 * K + k0 + c0),
                (__attribute__((address_space(3))) void*)(Blds + wid * 512), 16, 0, 0);
            __builtin_amdgcn_global_load_lds(
                (const __attribute__((address_space(1))) void*)(B + Bbase + (long)r1 * K + k0 + c1),
                (__attribute__((address_space(3))) void*)(Blds + 2048 + wid * 512), 16, 0, 0);
            __syncthreads();

            bf16x8 af[4], bfr[4];
            #pragma unroll
            for (int m = 0; m < 4; m++)
                af[m] = *reinterpret_cast<const bf16x8*>(&Alds[(arow + m * 16) * 32 + koff]);
            #pragma unroll
            for (int n = 0; n < 4; n++)
                bfr[n] = *reinterpret_cast<const bf16x8*>(&Blds[(brow + n * 16) * 32 + koff]);
            #pragma unroll
            for (int m = 0; m < 4; m++)
                #pragma unroll
                for (int n = 0; n < 4; n++)
                    acc[m][n] = __builtin_amdgcn_mfma_f32_16x16x32_bf16(af[m], bfr[n], acc[m][n], 0, 0, 0);
            __syncthreads();
        }

        const int crow0 = bm * 128 + wr * 64 + ((lane >> 4) << 2);
        const int ccol0 = bn * 128 + wc * 64 + (lane & 15);
        #pragma unroll
        for (int m = 0; m < 4; m++)
            #pragma unroll
            for (int j = 0; j < 4; j++) {
                const long r = crow0 + m * 16 + j;
                #pragma unroll
                for (int n = 0; n < 4; n++)
                    C[r * N + ccol0 + n * 16] = f2bf(acc[m][n][j]);
            }
    } else {
        const int row = blockIdx.x - 256;
        const float4* x4 = reinterpret_cast<const float4*>(x + (long)row * D_MODEL);
        float4 a = x4[t];
        float4 b = x4[256 + t];
        float s  = a.x + a.y + a.z + a.w + b.x + b.y + b.z + b.w;
        float ss = a.x*a.x + a.y*a.y + a.z*a.z + a.w*a.w
                 + b.x*b.x + b.y*b.y + b.z*b.z + b.w*b.w;
        #pragma unroll
        for (int off = 32; off; off >>= 1) {
            s  += __shfl_xor(s, off);
            ss += __shfl_xor(ss, off);
        }
        float* red = reinterpret_cast<float*>(Alds);
        const int lane = t & 63, wid = t >> 6;
        if (lane == 0) { red[wid*2] = s; red[wid*2+1] = ss; }
        __syncthreads();
        s  = red[0] + red[2] + red[4] + red[6];
        ss = red[1] + red[3] + red[5] + red[7];
        const float mean = s * (1.0f / D_MODEL);
        const float var  = ss * (1.0f / D_MODEL) - mean * mean;
        const float inv  = rsqrtf(var + 1e-5f);

        const float4* g4  = reinterpret_cast<const float4*>(gamma);
        const float4* be4 = reinterpret_cast<const float4*>(beta);
        ushort4* h4 = reinterpret_cast<ushort4*>(h + (long)row * D_MODEL);
        {
            float4 g = g4[t], be = be4[t];
            ushort4 o;
            o.x = f2bf((a.x - mean) * inv * g.x + be.x);
            o.y = f2bf((a.y - mean) * inv * g.y + be.y);
            o.z = f2bf((a.z - mean) * inv * g.z + be.z);
            o.w = f2bf((a.w - mean) * inv * g.w + be.w);
            h4[t] = o;
        }
        {
            float4 g = g4[256 + t], be = be4[256 + t];
            ushort4 o;
            o.x = f2bf((b.x - mean) * inv * g.x + be.x);
            o.y = f2bf((b.y - mean) * inv * g.y + be.y);
            o.z = f2bf((b.z - mean) * inv * g.z + be.z);
            o.w = f2bf((b.w - mean) * inv * g.w + be.w);
            h4[256 + t] = o;
        }
    }
}

// ======== K3: big BT-GEMM, 256x256 8-phase (r9 K-loop) + LDS-coalesced epilogue ========
// C[m][n] = sum_k A[m][k]*B[n][k] + bias[n] + resid[m][n], fp32 out.
// K-loop identical to round 9 (166 us proven): relaxed intra-phase schedule,
// one barrier/phase, counted vmcnt(4) at ph4/ph8, r2-proven swizzle.
// EPILOGUE (r10 change): stage C quadrants through LDS (free after K-loop),
// 4 fully-unrolled rounds of 64 rows (64 x 260 fp32, +4-pad), then each wave
// stores whole 256-col row segments: one float4/lane = 1 KB contiguous per
// instruction; resid read identically coalesced.  Replaces 4x64-B scattered
// segments/instr with dense 1-KB streams.  Bias folded at LDS-write.
#define GLL(src, dst) __builtin_amdgcn_global_load_lds( \
    (const __attribute__((address_space(1))) void*)(src), \
    (__attribute__((address_space(3))) void*)(dst), 16, 0, 0)
#define WAITV4() do { asm volatile("s_waitcnt vmcnt(4)" ::: "memory"); \
                      __builtin_amdgcn_sched_barrier(0); } while (0)
#define WAITV0() do { asm volatile("s_waitcnt vmcnt(0)" ::: "memory"); \
                      __builtin_amdgcn_sched_barrier(0); } while (0)

__global__ __launch_bounds__(512, 2) void gemm_bt_8ph(
    const unsigned short* __restrict__ A, const unsigned short* __restrict__ B,
    float* __restrict__ C, const float* __restrict__ bias,
    const float* __restrict__ resid, int M, int N, int K)
{
    __shared__ __align__(16) char ldsb[131072];

    const int nBN = N >> 8;             // 8
    int wg = blockIdx.x;
    const int cpx = gridDim.x >> 3;     // 512 % 8 == 0
    wg = (wg & 7) * cpx + (wg >> 3);
    const int bm = wg / nBN, bn = wg % nBN;

    const int t = threadIdx.x;
    const int lane = t & 63, wid = t >> 6;
    const int wr = wid >> 2;            // 0..1
    const int wc = wid & 3;             // 0..3

    // ---- staging addressing (inverse-swizzled source) ----
    const long Kl = K;
    const int tr = t >> 3;                                  // row 0..63
    const int c8 = ((t & 7) ^ (tr & 7)) * 8;                // source k-chunk
    const unsigned short* As = A + (long)(bm * 256 + tr) * Kl + c8;
    const unsigned short* Bs = B + (long)(bn * 256 + tr) * Kl + c8;

#define ST_A(buf, half, kcol) do { \
    const unsigned short* s_ = As + (half) * 128 * Kl + (kcol); \
    char* d_ = ldsb + (buf) * 65536 + (half) * 16384 + t * 16; \
    GLL(s_, d_); GLL(s_ + 64 * Kl, d_ + 8192); } while (0)
#define ST_B(buf, half, kcol) do { \
    const unsigned short* s_ = Bs + (half) * 128 * Kl + (kcol); \
    char* d_ = ldsb + (buf) * 65536 + 32768 + (half) * 16384 + t * 16; \
    GLL(s_, d_); GLL(s_ + 64 * Kl, d_ + 8192); } while (0)

    // ---- ds_read addressing (swizzled) ----
    const int l15 = lane & 15, l4 = lane >> 4;
    const int swz0 = ((l4)     ^ (l15 & 7)) << 4;           // kk=0
    const int swz1 = ((4 + l4) ^ (l15 & 7)) << 4;           // kk=1
    const int aOff = wr * 16384 + l15 * 128;
    const int bOff = 32768 + (wc >> 1) * 16384 + ((wc & 1) * 64 + l15) * 128;

#define LDV(off) (*reinterpret_cast<const bf16x8*>(ldsb + (off)))
#define RD_A(buf, mh) do { \
    _Pragma("unroll") for (int mi = 0; mi < 4; ++mi) \
        af[mi][0] = LDV((buf) * 65536 + aOff + ((mh) * 4 + mi) * 2048 + swz0); \
    _Pragma("unroll") for (int mi = 0; mi < 4; ++mi) \
        af[mi][1] = LDV((buf) * 65536 + aOff + ((mh) * 4 + mi) * 2048 + swz1); } while (0)
#define RD_B0(buf) do { \
    _Pragma("unroll") for (int nj = 0; nj < 2; ++nj) \
        b0[nj][0] = LDV((buf) * 65536 + bOff + nj * 2048 + swz0); \
    _Pragma("unroll") for (int nj = 0; nj < 2; ++nj) \
        b0[nj][1] = LDV((buf) * 65536 + bOff + nj * 2048 + swz1); } while (0)
#define RD_B1(buf) do { \
    _Pragma("unroll") for (int nj = 0; nj < 2; ++nj) \
        b1[nj][0] = LDV((buf) * 65536 + bOff + (2 + nj) * 2048 + swz0); \
    _Pragma("unroll") for (int nj = 0; nj < 2; ++nj) \
        b1[nj][1] = LDV((buf) * 65536 + bOff + (2 + nj) * 2048 + swz1); } while (0)

#define MMQ(mh, nh, BQ) do { \
    __builtin_amdgcn_s_setprio(1); \
    _Pragma("unroll") for (int kk = 0; kk < 2; ++kk) \
    _Pragma("unroll") for (int mi = 0; mi < 4; ++mi) \
    _Pragma("unroll") for (int nj = 0; nj < 2; ++nj) \
        acc[(mh) * 4 + mi][(nh) * 2 + nj] = __builtin_amdgcn_mfma_f32_16x16x32_bf16( \
            af[mi][kk], BQ[nj][kk], acc[(mh) * 4 + mi][(nh) * 2 + nj], 0, 0, 0); \
    __builtin_amdgcn_s_setprio(0); } while (0)
#define ENDP() __builtin_amdgcn_s_barrier()

    bf16x8 af[4][2], b0[2][2], b1[2][2];
    f32x4 acc[8][4];
    #pragma unroll
    for (int i = 0; i < 8; i++)
        #pragma unroll
        for (int j = 0; j < 4; j++) acc[i][j] = (f32x4){0.f, 0.f, 0.f, 0.f};

    const int NI = K >> 7;              // 16 iterations, 2 K-tiles each

    // prologue: buf0 (4 halves) + B1h0 + A1h0 of K-tile 1 (12 loads)
    ST_A(0, 0, 0); ST_A(0, 1, 0); ST_B(0, 0, 0); ST_B(0, 1, 0);
    ST_B(1, 0, 64); ST_A(1, 0, 64);
    WAITV4();                           // buf0's 8 retired; tile-1 h0s in flight
    __builtin_amdgcn_s_barrier();

    for (int i = 0; i < NI; ++i) {
        const int kcA1 = (i << 7) + 64;          // K-tile 2i+1 (buf1, this iter)
        const int kcN0 = (i << 7) + 128;         // K-tile 2i+2 (buf0, next iter)
        const int kcN1 = (i << 7) + 192;         // K-tile 2i+3 (buf1, next iter)
        const bool more = (i + 1 < NI);

        // ph1: Q(0,0) buf0 ; stage buf1-A h1
        RD_A(0, 0); RD_B0(0);
        ST_A(1, 1, kcA1);
        MMQ(0, 0, b0); ENDP();
        // ph2: Q(0,1) ; stage buf1-B h1
        RD_B1(0);
        ST_B(1, 1, kcA1);
        MMQ(0, 1, b1); ENDP();
        // ph3: Q(1,0) ; stage buf0-B h0 (next pair)
        RD_A(0, 1);
        if (more) ST_B(0, 0, kcN0);
        MMQ(1, 0, b0); ENDP();
        // ph4: Q(1,1) ; stage buf0-A h0 ; wait buf1 resident
        if (more) ST_A(0, 0, kcN0);
        MMQ(1, 1, b1);
        if (more) { WAITV4(); } else { WAITV0(); }
        ENDP();
        // ph5: Q(0,0) buf1 ; stage buf0-A h1
        RD_A(1, 0); RD_B0(1);
        if (more) ST_A(0, 1, kcN0);
        MMQ(0, 0, b0); ENDP();
        // ph6: Q(0,1) ; stage buf0-B h1
        RD_B1(1);
        if (more) ST_B(0, 1, kcN0);
        MMQ(0, 1, b1); ENDP();
        // ph7: Q(1,0) ; stage buf1-B h0 (tile 2i+3)
        RD_A(1, 1);
        if (more) ST_B(1, 0, kcN1);
        MMQ(1, 0, b0); ENDP();
        // ph8: Q(1,1) ; stage buf1-A h0 (tile 2i+3) ; wait buf0 resident
        if (more) ST_A(1, 0, kcN1);
        MMQ(1, 1, b1);
        if (more) { WAITV4(); }
        ENDP();
    }
#undef ST_A
#undef ST_B
#undef RD_A
#undef RD_B0
#undef RD_B1
#undef MMQ
#undef ENDP
#undef LDV

    // ---- epilogue: LDS-staged, fully-coalesced stores ----
    // 4 rounds x 64 rows; LDS layout [64][260] fp32 (pad 4 -> write 2-way free,
    // b128 readback conflict-free).  acc rows: wr*128 + m*16 + l4*4 + j.
    // Round rd covers global rows bm*256 + rd*64 ..+64; owner waves wr==rd>>1,
    // m in [(rd&1)*4, +4).  Store phase: wave wid -> rows wid*8..+8; col = lane*4.
    float* ldsf = reinterpret_cast<float*>(ldsb);
    float bias4[4];
    #pragma unroll
    for (int n = 0; n < 4; n++)
        bias4[n] = bias[bn * 256 + wc * 64 + l15 + n * 16];
    const int wcol = wc * 64 + l15;

    #pragma unroll
    for (int rd = 0; rd < 4; ++rd) {
        __syncthreads();                 // prev round's reads done / K-loop done
        if (wr == (rd >> 1)) {
            #pragma unroll
            for (int mm = 0; mm < 4; ++mm) {
                const int m = (rd & 1) * 4 + mm;
                #pragma unroll
                for (int j = 0; j < 4; ++j) {
                    const int rl = mm * 16 + l4 * 4 + j;
                    #pragma unroll
                    for (int n = 0; n < 4; ++n)
                        ldsf[rl * 260 + wcol + n * 16] = acc[m][n][j] + bias4[n];
                }
            }
        }
        __syncthreads();
        const long gr0 = (long)bm * 256 + rd * 64;
        #pragma unroll
        for (int rr = 0; rr < 8; ++rr) {
            const int rl = wid * 8 + rr;
            const long go = (gr0 + rl) * N + bn * 256 + lane * 4;
            float4 v = *reinterpret_cast<const float4*>(&ldsf[rl * 260 + lane * 4]);
            const float4 rv = *reinterpret_cast<const float4*>(&resid[go]);
            v.x += rv.x; v.y += rv.y; v.z += rv.z; v.w += rv.w;
            *reinterpret_cast<float4*>(&C[go]) = v;
        }
    }
}

extern "C" void kernel_launch(void* const* d_in, const int* in_sizes, int n_in,
                              void* d_out, int out_size, void* d_ws, size_t ws_size,
                              hipStream_t stream) {
    // setup_inputs order: x, w_q, b_q, w_k, b_k, w_v, b_v, w_o, b_o, ln_gamma, ln_beta
    const float* x     = (const float*)d_in[0];
    const float* w_v   = (const float*)d_in[5];
    const float* b_v   = (const float*)d_in[6];
    const float* w_o   = (const float*)d_in[7];
    const float* b_o   = (const float*)d_in[8];
    const float* gamma = (const float*)d_in[9];
    const float* beta  = (const float*)d_in[10];
    float* out = (float*)d_out;

    char* ws = (char*)d_ws;
    unsigned short* h   = (unsigned short*)(ws);                              // 64 MiB
    unsigned short* wvT = (unsigned short*)(ws + 67108864L);                  // 8 MiB
    unsigned short* woB = (unsigned short*)(ws + 67108864L + 8388608L);       // 8 MiB
    unsigned short* Wc  = (unsigned short*)(ws + 67108864L + 2 * 8388608L);   // 8 MiB
    float*          b_c = (float*)(ws + 67108864L + 3 * 8388608L);            // 8 KiB

    // K1: transpose(w_v) || convert(w_o) || bias-combine
    prep_kernel<<<8192, 256, 0, stream>>>(w_v, w_o, b_v, b_o, wvT, woB, b_c);
    // K2: Wc = woB . wvT^T (blocks 0-255) || h = LN(x) (blocks 256+)
    lnwc_kernel<<<256 + N_BATCH, 256, 0, stream>>>(woB, wvT, Wc, x, gamma, beta, h);
    // K3: out = h . Wc^T + b_c + x
    gemm_bt_8ph<<<(N_BATCH / 256) * (D_MODEL / 256), 512, 0, stream>>>(
        h, Wc, out, b_c, x, N_BATCH, D_MODEL, D_MODEL);
}